// Round 2
// baseline (1644.443 us; speedup 1.0000x reference)
//
#include <hip/hip_runtime.h>

// Attention_Critic on MI355X — round 2: dtype-robust correct baseline.
// NaN post-mortem: round-1 read inputs as bf16; if they are f32 the low-u16
// halves have random exponent fields -> NaN patterns -> BN sums go NaN.
// Fix: device-side dtype detection (k_detect) + flag-branched loaders.
// Intermediates (E/SE/OT) are always bf16 in ws; LDS weights are f32.
//
// ws layout (bytes):
//   [0,256)        int flag   (1 = bf16 inputs, 0 = f32 inputs)
//   [256, +163840) stats partials f32 [8 agents][32 chunks][80 feat][2]
//   [164096,+5120) mean/rsig f32 [8][80][2]
//   [169216,+32MB) E  bf16 [8][16384][128]
//   [+32MB, +64MB) SE bf16 [8][16384][128]
//   [+64MB, +96MB) OT bf16 [8][16384][128] (other_flat)
// total ~96.2 MiB.

typedef unsigned short u16;
typedef unsigned int u32;

#define NA 8
#define BATCH 16384
#define SD 64
#define AD 16
#define IND 80
#define SANP 81   // san leading-dim pad (+1) to break 16*80*4B same-bank stride
#define HID 128
#define HEADS 4
#define ATT 32
#define EPS 1e-5f

__device__ __forceinline__ float bf2f(u16 u) { union { u32 i; float f; } v; v.i = ((u32)u) << 16; return v.f; }
__device__ __forceinline__ float lo2f(u32 w) { union { u32 i; float f; } v; v.i = w << 16; return v.f; }
__device__ __forceinline__ float hi2f(u32 w) { union { u32 i; float f; } v; v.i = w & 0xffff0000u; return v.f; }
__device__ __forceinline__ u16 f2bf(float f) {
  union { float f; u32 i; } v; v.f = f;
  u32 x = v.i;
  x += 0x7fffu + ((x >> 16) & 1u);   // round-to-nearest-even
  return (u16)(x >> 16);
}
__device__ __forceinline__ float lrelu(float x) { return x > 0.f ? x : 0.01f * x; }
// flag-branched input load: wave-uniform branch, negligible cost
__device__ __forceinline__ float ldin(const void* p, size_t i, bool bf) {
  return bf ? bf2f(((const u16*)p)[i]) : ((const float*)p)[i];
}

// ---------------- K0: input dtype detection ----------------
// Examine first 256 u32 words of s (N(0,1) data, never ~0).
// bf16 data: low u16 of each word is a sane bf16 (exp in [0x70,0x8f]) -> insane ~ 0.
// generic f32: low u16 = random mantissa bits -> insane ~ 224.
// bf16-rounded-then-upcast f32: low u16 == 0 -> zeros ~ 256 (that buffer IS f32).
__global__ __launch_bounds__(64) void k_detect(const u32* __restrict__ s, int* __restrict__ flag) {
  int t = threadIdx.x;
  int insane = 0, zeros = 0;
  for (int i = t; i < 256; i += 64) {
    u32 lo = s[i] & 0xffffu;
    u32 e = (lo >> 7) & 0xffu;
    if (lo == 0u || lo == 0x8000u) zeros++;
    else if (e < 0x70u || e > 0x8fu) insane++;
  }
  for (int o = 32; o; o >>= 1) { insane += __shfl_down(insane, o); zeros += __shfl_down(zeros, o); }
  if (t == 0) {
    int bf = 1;
    if (insane >= 64) bf = 0;       // generic f32
    else if (zeros >= 192) bf = 0;  // bf16-valued f32 buffer
    *flag = bf;
  }
}

// ---------------- K1a: per-(agent,feature) partial sums over a 512-batch chunk ----------------
__global__ __launch_bounds__(256) void k_stats(const void* __restrict__ s, const void* __restrict__ a,
                                               const int* __restrict__ flag, float* __restrict__ part) {
  __shared__ float red[512];
  bool bf = (*flag != 0);
  int tid = threadIdx.x;
  int blk = blockIdx.x;          // n*32 + c
  int n = blk >> 5, c = blk & 31;
  int b0 = c << 9;               // c*512
  {
    int f = tid & 63, bsub = tid >> 6;
    size_t base = (size_t)n * BATCH * SD;
    float sum = 0.f, sq = 0.f;
    for (int b = b0 + bsub; b < b0 + 512; b += 4) {
      float x = ldin(s, base + (size_t)b * SD + f, bf);
      sum += x; sq += x * x;
    }
    red[tid] = sum; red[256 + tid] = sq;
  }
  __syncthreads();
  if (tid < 64) {
    float S = red[tid] + red[tid + 64] + red[tid + 128] + red[tid + 192];
    float Q = red[256 + tid] + red[256 + tid + 64] + red[256 + tid + 128] + red[256 + tid + 192];
    float* p = part + ((size_t)blk * IND + tid) * 2;
    p[0] = S; p[1] = Q;
  }
  __syncthreads();
  {
    int f = tid & 15, bsub = tid >> 4;
    size_t base = (size_t)n * BATCH * AD;
    float sum = 0.f, sq = 0.f;
    for (int b = b0 + bsub; b < b0 + 512; b += 16) {
      float x = ldin(a, base + (size_t)b * AD + f, bf);
      sum += x; sq += x * x;
    }
    red[tid] = sum; red[256 + tid] = sq;
  }
  __syncthreads();
  if (tid < 16) {
    float S = 0.f, Q = 0.f;
    for (int g = 0; g < 16; g++) { S += red[g * 16 + tid]; Q += red[256 + g * 16 + tid]; }
    float* p = part + ((size_t)blk * IND + SD + tid) * 2;
    p[0] = S; p[1] = Q;
  }
}

// ---------------- K1b: finalize mean / rsqrt(var+eps) ----------------
__global__ __launch_bounds__(64) void k_stats_fin(const float* __restrict__ part, float* __restrict__ mr) {
  int i = blockIdx.x * 64 + threadIdx.x;
  if (i >= NA * IND) return;
  int n = i / IND, f = i - n * IND;
  float S = 0.f, Q = 0.f;
  for (int c = 0; c < 32; c++) {
    const float* p = part + ((size_t)(n * 32 + c) * IND + f) * 2;
    S += p[0]; Q += p[1];
  }
  float mean = S * (1.f / BATCH);
  float var = Q * (1.f / BATCH) - mean * mean;   // biased var
  mr[i * 2] = mean;
  mr[i * 2 + 1] = rsqrtf(var + EPS);
}

// ---------------- K2: encoders E = lrelu(bn(sa)@W_sa+b), SE = lrelu(bn(s)@W_se+b) ----------------
// One block = one agent x 64 batch rows. Normalized rows staged once, two weight passes.
// LDS: Wf 40KB + san 20.7KB + mst 0.64KB = ~61.4KB
__global__ __launch_bounds__(256) void k_enc(const void* __restrict__ s, const void* __restrict__ a,
    const void* __restrict__ Wsa, const void* __restrict__ bsa,
    const void* __restrict__ Wse, const void* __restrict__ bse,
    const float* __restrict__ mr, const int* __restrict__ flag,
    u16* __restrict__ E, u16* __restrict__ SEo) {
  __shared__ float Wf[IND * HID];     // pass1: Wsa 80x128; pass2: Wse 64x128 (reuse)
  __shared__ float san[64 * SANP];
  __shared__ float mst[IND * 2];
  bool bf = (*flag != 0);
  int tid = threadIdx.x;
  int n = blockIdx.y;
  int b0 = blockIdx.x * 64;
  if (tid < IND * 2) mst[tid] = mr[n * IND * 2 + tid];
  __syncthreads();
  for (int i = tid; i < 64 * IND; i += 256) {
    int r = i / IND, f = i - r * IND;
    float x = (f < SD) ? ldin(s, ((size_t)n * BATCH + b0 + r) * SD + f, bf)
                       : ldin(a, ((size_t)n * BATCH + b0 + r) * AD + (f - SD), bf);
    san[r * SANP + f] = (x - mst[f * 2]) * mst[f * 2 + 1];
  }
  for (int i = tid; i < IND * HID; i += 256) Wf[i] = ldin(Wsa, (size_t)n * IND * HID + i, bf);
  __syncthreads();
  int h2 = tid & 63, bl = tid >> 6;    // 64 col-pairs x 4 row-groups(16 rows each)
  {
    float bv0 = ldin(bsa, n * HID + 2 * h2, bf), bv1 = ldin(bsa, n * HID + 2 * h2 + 1, bf);
    float acc0[16], acc1[16];
    #pragma unroll
    for (int r = 0; r < 16; r++) { acc0[r] = bv0; acc1[r] = bv1; }
    for (int k = 0; k < IND; k++) {
      float w0 = Wf[k * HID + 2 * h2], w1 = Wf[k * HID + 2 * h2 + 1];
      #pragma unroll
      for (int r = 0; r < 16; r++) {
        float x = san[(bl * 16 + r) * SANP + k];
        acc0[r] = fmaf(x, w0, acc0[r]);
        acc1[r] = fmaf(x, w1, acc1[r]);
      }
    }
    #pragma unroll
    for (int r = 0; r < 16; r++) {
      int b = b0 + bl * 16 + r;
      ((u32*)E)[((size_t)n * BATCH + b) * (HID / 2) + h2] =
          (u32)f2bf(lrelu(acc0[r])) | ((u32)f2bf(lrelu(acc1[r])) << 16);
    }
  }
  __syncthreads();
  for (int i = tid; i < SD * HID; i += 256) Wf[i] = ldin(Wse, (size_t)n * SD * HID + i, bf);
  __syncthreads();
  {
    float bv0 = ldin(bse, n * HID + 2 * h2, bf), bv1 = ldin(bse, n * HID + 2 * h2 + 1, bf);
    float acc0[16], acc1[16];
    #pragma unroll
    for (int r = 0; r < 16; r++) { acc0[r] = bv0; acc1[r] = bv1; }
    for (int k = 0; k < SD; k++) {
      float w0 = Wf[k * HID + 2 * h2], w1 = Wf[k * HID + 2 * h2 + 1];
      #pragma unroll
      for (int r = 0; r < 16; r++) {
        float x = san[(bl * 16 + r) * SANP + k];
        acc0[r] = fmaf(x, w0, acc0[r]);
        acc1[r] = fmaf(x, w1, acc1[r]);
      }
    }
    #pragma unroll
    for (int r = 0; r < 16; r++) {
      int b = b0 + bl * 16 + r;
      ((u32*)SEo)[((size_t)n * BATCH + b) * (HID / 2) + h2] =
          (u32)f2bf(lrelu(acc0[r])) | ((u32)f2bf(lrelu(acc1[r])) << 16);
    }
  }
}

// ---------------- K3: fused head projections + masked softmax attention ----------------
// block = 8 batch elements x all 8 agents.
// LDS: xf 16K (bf16) + selt 16K + wt 8K (f32; lg aliases) + kt 4K + vt 4K = 48KB
__global__ __launch_bounds__(256) void k_attn(
    const u16* __restrict__ E, const u16* __restrict__ SEi,
    const void* __restrict__ Wk_g, const void* __restrict__ Wsl_g, const void* __restrict__ Wv_g,
    const void* __restrict__ bv_g, const int* __restrict__ flag, u16* __restrict__ OT) {
  __shared__ u16 xf[NA * 8 * HID];            // staged e or se rows (bf16, straight copy)
  __shared__ u16 selt[HEADS * NA * 8 * ATT];
  __shared__ float wt[64 * ATT];              // one K-half of one proj matrix, f32 (lg aliases)
  __shared__ u16 kt[NA * 8 * ATT];
  __shared__ u16 vt[NA * 8 * ATT];
  bool bf = (*flag != 0);
  int tid = threadIdx.x;
  int b0 = blockIdx.x * 8;
  int nn = tid >> 5, d = tid & 31;

  // ---- phase A: selt[p] = se @ Wsel[p] ----
  {
    const u32* su = (const u32*)SEi;
    u32* xu = (u32*)xf;
    for (int i = tid; i < NA * 8 * (HID / 2); i += 256) {
      int n = i >> 9, r = i & 511, b = r >> 6, h2 = r & 63;
      xu[i] = su[((size_t)n * BATCH + b0 + b) * (HID / 2) + h2];
    }
  }
  __syncthreads();
  for (int p = 0; p < HEADS; p++) {
    float acc[8] = {0.f,0.f,0.f,0.f,0.f,0.f,0.f,0.f};
    for (int ph = 0; ph < 2; ph++) {
      size_t wb = ((size_t)p * HID + ph * 64) * ATT;
      for (int i = tid; i < 64 * ATT; i += 256) wt[i] = ldin(Wsl_g, wb + i, bf);
      __syncthreads();
      for (int kc = 0; kc < 64; kc += 8) {
        float w8[8];
        #pragma unroll
        for (int j = 0; j < 8; j++) w8[j] = wt[(kc + j) * ATT + d];
        #pragma unroll
        for (int b = 0; b < 8; b++) {
          const u32* xr = (const u32*)&xf[(nn * 8 + b) * HID + ph * 64 + kc];
          #pragma unroll
          for (int j2 = 0; j2 < 4; j2++) {
            u32 xv = xr[j2];
            acc[b] = fmaf(lo2f(xv), w8[2 * j2], acc[b]);
            acc[b] = fmaf(hi2f(xv), w8[2 * j2 + 1], acc[b]);
          }
        }
      }
      __syncthreads();
    }
    #pragma unroll
    for (int b = 0; b < 8; b++) selt[((p * NA + nn) * 8 + b) * ATT + d] = f2bf(acc[b]);
  }
  __syncthreads();
  // ---- phase B: xf <- e ----
  {
    const u32* su = (const u32*)E;
    u32* xu = (u32*)xf;
    for (int i = tid; i < NA * 8 * (HID / 2); i += 256) {
      int n = i >> 9, r = i & 511, b = r >> 6, h2 = r & 63;
      xu[i] = su[((size_t)n * BATCH + b0 + b) * (HID / 2) + h2];
    }
  }
  __syncthreads();
  float* lg = (float*)wt;   // 8i x 8b x 8j logits/weights (2KB, aliases wt)
  for (int p = 0; p < HEADS; p++) {
    // keys = e @ Wk[p]
    {
      float acc[8] = {0.f,0.f,0.f,0.f,0.f,0.f,0.f,0.f};
      for (int ph = 0; ph < 2; ph++) {
        size_t wb = ((size_t)p * HID + ph * 64) * ATT;
        for (int i = tid; i < 64 * ATT; i += 256) wt[i] = ldin(Wk_g, wb + i, bf);
        __syncthreads();
        for (int kc = 0; kc < 64; kc += 8) {
          float w8[8];
          #pragma unroll
          for (int j = 0; j < 8; j++) w8[j] = wt[(kc + j) * ATT + d];
          #pragma unroll
          for (int b = 0; b < 8; b++) {
            const u32* xr = (const u32*)&xf[(nn * 8 + b) * HID + ph * 64 + kc];
            #pragma unroll
            for (int j2 = 0; j2 < 4; j2++) {
              u32 xv = xr[j2];
              acc[b] = fmaf(lo2f(xv), w8[2 * j2], acc[b]);
              acc[b] = fmaf(hi2f(xv), w8[2 * j2 + 1], acc[b]);
            }
          }
        }
        __syncthreads();
      }
      #pragma unroll
      for (int b = 0; b < 8; b++) kt[(nn * 8 + b) * ATT + d] = f2bf(acc[b]);
    }
    // vals = lrelu(e @ Wv[p] + bv[p])
    {
      float acc[8] = {0.f,0.f,0.f,0.f,0.f,0.f,0.f,0.f};
      for (int ph = 0; ph < 2; ph++) {
        size_t wb = ((size_t)p * HID + ph * 64) * ATT;
        for (int i = tid; i < 64 * ATT; i += 256) wt[i] = ldin(Wv_g, wb + i, bf);
        __syncthreads();
        for (int kc = 0; kc < 64; kc += 8) {
          float w8[8];
          #pragma unroll
          for (int j = 0; j < 8; j++) w8[j] = wt[(kc + j) * ATT + d];
          #pragma unroll
          for (int b = 0; b < 8; b++) {
            const u32* xr = (const u32*)&xf[(nn * 8 + b) * HID + ph * 64 + kc];
            #pragma unroll
            for (int j2 = 0; j2 < 4; j2++) {
              u32 xv = xr[j2];
              acc[b] = fmaf(lo2f(xv), w8[2 * j2], acc[b]);
              acc[b] = fmaf(hi2f(xv), w8[2 * j2 + 1], acc[b]);
            }
          }
        }
        __syncthreads();
      }
      float bvv = ldin(bv_g, p * ATT + d, bf);
      #pragma unroll
      for (int b = 0; b < 8; b++) vt[(nn * 8 + b) * ATT + d] = f2bf(lrelu(acc[b] + bvv));
    }
    __syncthreads();   // kt, vt visible; wt region now free -> lg
    // logits[i][b][j] = sel_i . key_j / sqrt(32), self-masked
    {
      int j = tid & 7, b = (tid >> 3) & 7, i0 = tid >> 6;
      for (int ii = i0; ii < 8; ii += 4) {
        float lv;
        if (ii == j) {
          lv = -1e9f;
        } else {
          const u32* sp = (const u32*)&selt[((p * NA + ii) * 8 + b) * ATT];
          const u32* kp = (const u32*)&kt[(j * 8 + b) * ATT];
          float acc = 0.f;
          #pragma unroll
          for (int d2 = 0; d2 < 16; d2++) {
            u32 sv = sp[d2], kv = kp[d2];
            acc = fmaf(lo2f(sv), lo2f(kv), acc);
            acc = fmaf(hi2f(sv), hi2f(kv), acc);
          }
          lv = acc * 0.17677669529663687f;
        }
        lg[(ii * 8 + b) * 8 + j] = lv;
      }
    }
    __syncthreads();
    // softmax over j
    if (tid < 64) {
      int i = tid >> 3, b = tid & 7;
      float* row = &lg[(i * 8 + b) * 8];
      float m = row[0];
      #pragma unroll
      for (int j = 1; j < 8; j++) m = fmaxf(m, row[j]);
      float ex[8]; float ssum = 0.f;
      #pragma unroll
      for (int j = 0; j < 8; j++) { ex[j] = __expf(row[j] - m); ssum += ex[j]; }
      float inv = 1.f / ssum;
      #pragma unroll
      for (int j = 0; j < 8; j++) row[j] = ex[j] * inv;
    }
    __syncthreads();
    // other[i][b][d] -> other_flat[i][b][p*32+d]
    {
      int g = tid >> 5;
      for (int pr = g * 8; pr < g * 8 + 8; pr++) {
        int i = pr >> 3, b = pr & 7;
        float acc = 0.f;
        #pragma unroll
        for (int j = 0; j < 8; j++)
          acc = fmaf(lg[(i * 8 + b) * 8 + j], bf2f(vt[(j * 8 + b) * ATT + d]), acc);
        OT[((size_t)i * BATCH + b0 + b) * HID + p * ATT + d] = f2bf(acc);
      }
    }
    __syncthreads();   // before next head's wt staging overwrites lg
  }
}

// ---------------- K4: critic MLP + argmax gather ----------------
// LDS: W1 32KB (64 K-rows, f32) + xrow 16KB + wc2 8KB + amax = ~56.1KB
__global__ __launch_bounds__(256) void k_critic(
    const u16* __restrict__ SEi, const u16* __restrict__ OT, const void* __restrict__ a_g,
    const void* __restrict__ Wc1_g, const void* __restrict__ bc1_g,
    const void* __restrict__ Wc2_g, const void* __restrict__ bc2_g,
    const int* __restrict__ flag, void* __restrict__ qo) {
  __shared__ float W1[64 * HID];
  __shared__ float xrow[32 * HID];   // later aliased as ht (bf16)
  __shared__ float wc2[HID * AD];
  __shared__ int amax[32];
  bool bf = (*flag != 0);
  int tid = threadIdx.x;
  int n = blockIdx.y;
  int b0 = blockIdx.x * 32;
  int h = tid & 127, half = tid >> 7;
  float acc[16];
  #pragma unroll
  for (int i = 0; i < 16; i++) acc[i] = 0.f;
  for (int ph = 0; ph < 2; ph++) {
    const u16* xsrc = (ph == 0) ? SEi : OT;   // critic_in = [se | other_flat]
    for (int i = tid; i < 32 * HID; i += 256) {
      int b = i >> 7, hh = i & 127;
      xrow[i] = bf2f(xsrc[((size_t)n * BATCH + b0 + b) * HID + hh]);
    }
    for (int g = 0; g < 2; g++) {   // 64 K-rows per stage
      for (int i = tid; i < 64 * HID; i += 256) {
        int k = i >> 7, hh = i & 127;
        W1[i] = ldin(Wc1_g, ((size_t)n * 2 * HID + ph * HID + g * 64 + k) * HID + hh, bf);
      }
      __syncthreads();
      for (int k = 0; k < 64; k++) {
        float wf = W1[k * HID + h];
        #pragma unroll
        for (int bi = 0; bi < 16; bi++)
          acc[bi] = fmaf(xrow[(half * 16 + bi) * HID + g * 64 + k], wf, acc[bi]);
      }
      __syncthreads();
    }
  }
  float b1 = ldin(bc1_g, n * HID + h, bf);
  u16* ht = (u16*)xrow;   // safe: all xrow reads done before last barrier
  #pragma unroll
  for (int bi = 0; bi < 16; bi++)
    ht[(half * 16 + bi) * HID + h] = f2bf(lrelu(acc[bi] + b1));
  for (int i = tid; i < HID * AD; i += 256) wc2[i] = ldin(Wc2_g, (size_t)n * HID * AD + i, bf);
  if (tid < 32) {
    size_t base = ((size_t)n * BATCH + b0 + tid) * AD;
    float best = ldin(a_g, base, bf); int bi = 0;
    for (int o = 1; o < AD; o++) {
      float v = ldin(a_g, base + o, bf);
      if (v > best) { best = v; bi = o; }   // strict > keeps FIRST max (np.argmax tie rule)
    }
    amax[tid] = bi;
  }
  __syncthreads();
  if (tid < 128) {
    int b = tid >> 2, part = tid & 3;
    int col = amax[b];
    float acq = 0.f;
    const u16* hr = &ht[b * HID + part * 32];
    #pragma unroll
    for (int k = 0; k < 32; k++)
      acq = fmaf(bf2f(hr[k]), wc2[(part * 32 + k) * AD + col], acq);
    acq += __shfl_xor(acq, 1);
    acq += __shfl_xor(acq, 2);
    if (part == 0) {
      float v = acq + ldin(bc2_g, n * AD + col, bf);
      size_t idx = (size_t)n * BATCH + b0 + b;
      if (bf) ((u16*)qo)[idx] = f2bf(v);
      else    ((float*)qo)[idx] = v;
    }
  }
}

extern "C" void kernel_launch(void* const* d_in, const int* in_sizes, int n_in,
                              void* d_out, int out_size, void* d_ws, size_t ws_size,
                              hipStream_t stream) {
  const void* s   = d_in[0];
  const void* a   = d_in[1];
  const void* Wsa = d_in[2];
  const void* bsa = d_in[3];
  const void* Wse = d_in[4];
  const void* bse = d_in[5];
  const void* Wk  = d_in[6];
  const void* Wsl = d_in[7];
  const void* Wv  = d_in[8];
  const void* bv  = d_in[9];
  const void* Wc1 = d_in[10];
  const void* bc1 = d_in[11];
  const void* Wc2 = d_in[12];
  const void* bc2 = d_in[13];

  char* ws = (char*)d_ws;
  int*   flag = (int*)ws;                                    // [0,256)
  float* part = (float*)(ws + 256);                          // 163840 B
  float* mr   = (float*)(ws + 256 + 163840);                 // 5120 B
  u16* E      = (u16*)(ws + 169216);                         // 32 MB
  u16* SEb    = (u16*)(ws + 169216 + 33554432ull);           // 32 MB
  u16* OT     = (u16*)(ws + 169216 + 2ull * 33554432ull);    // 32 MB

  k_detect<<<1, 64, 0, stream>>>((const u32*)s, flag);
  k_stats<<<256, 256, 0, stream>>>(s, a, flag, part);
  k_stats_fin<<<10, 64, 0, stream>>>(part, mr);
  k_enc<<<dim3(BATCH / 64, NA), 256, 0, stream>>>(s, a, Wsa, bsa, Wse, bse, mr, flag, E, SEb);
  k_attn<<<BATCH / 8, 256, 0, stream>>>(E, SEb, Wk, Wsl, Wv, bv, flag, OT);
  k_critic<<<dim3(BATCH / 32, NA), 256, 0, stream>>>(SEb, OT, a, Wc1, bc1, Wc2, bc2, flag, d_out);
}

// Round 3
// 753.403 us; speedup vs baseline: 2.1827x; 2.1827x over previous
//
#include <hip/hip_runtime.h>

// Attention_Critic on MI355X — round 3: MFMA for proj+attention (fused) and critic.
// stats/enc kept from round 2 (passing, small share). KEYS/VALS/SEL never
// materialized: computed per-block in LDS and consumed by the attention core.
//
// ws layout (bytes)  [unchanged, proven <= ws_size in round 2]:
//   [0,256)        int flag   (1 = bf16 inputs, 0 = f32 inputs)
//   [256, +163840) stats partials f32 [8][32][80][2]
//   [164096,+5120) mean/rsig f32 [8][80][2]
//   [169216,+32MB) E  bf16 [8][16384][128]
//   [+32MB, +64MB) SE bf16 [8][16384][128]
//   [+64MB, +96MB) OT bf16 [8][16384][128] (other_flat)

typedef unsigned short u16;
typedef unsigned int u32;

#define NA 8
#define BATCH 16384
#define SD 64
#define AD 16
#define IND 80
#define SANP 81
#define HID 128
#define HEADS 4
#define ATT 32
#define EPS 1e-5f
#define KP 136   // padded K leading dim (u16) for 128-K LDS tiles: row stride 272B -> lane bank stride 4 (2-way, free)
#define KP2 72   // padded K leading dim for 64-K W tiles in k_critic
#define SP 34    // padded row stride (u16) for 32-wide sel/key/val tiles (odd u32 stride -> conflict-free)

using short8 = __attribute__((ext_vector_type(8))) short;
using float4f = __attribute__((ext_vector_type(4))) float;
#define MFMA16(a, b, c) __builtin_amdgcn_mfma_f32_16x16x32_bf16((a), (b), (c), 0, 0, 0)

__device__ __forceinline__ float bf2f(u16 u) { union { u32 i; float f; } v; v.i = ((u32)u) << 16; return v.f; }
__device__ __forceinline__ float lo2f(u32 w) { union { u32 i; float f; } v; v.i = w << 16; return v.f; }
__device__ __forceinline__ float hi2f(u32 w) { union { u32 i; float f; } v; v.i = w & 0xffff0000u; return v.f; }
__device__ __forceinline__ u16 f2bf(float f) {
  union { float f; u32 i; } v; v.f = f;
  u32 x = v.i;
  x += 0x7fffu + ((x >> 16) & 1u);   // RNE
  return (u16)(x >> 16);
}
__device__ __forceinline__ float lrelu(float x) { return x > 0.f ? x : 0.01f * x; }
__device__ __forceinline__ float ldin(const void* p, size_t i, bool bf) {
  return bf ? bf2f(((const u16*)p)[i]) : ((const float*)p)[i];
}
// load input value as bf16 bit pattern (for MFMA operand staging)
__device__ __forceinline__ u16 ldbf(const void* p, size_t i, bool bf) {
  return bf ? ((const u16*)p)[i] : f2bf(((const float*)p)[i]);
}

// ---------------- K0: input dtype detection (unchanged) ----------------
__global__ __launch_bounds__(64) void k_detect(const u32* __restrict__ s, int* __restrict__ flag) {
  int t = threadIdx.x;
  int insane = 0, zeros = 0;
  for (int i = t; i < 256; i += 64) {
    u32 lo = s[i] & 0xffffu;
    u32 e = (lo >> 7) & 0xffu;
    if (lo == 0u || lo == 0x8000u) zeros++;
    else if (e < 0x70u || e > 0x8fu) insane++;
  }
  for (int o = 32; o; o >>= 1) { insane += __shfl_down(insane, o); zeros += __shfl_down(zeros, o); }
  if (t == 0) {
    int bf = 1;
    if (insane >= 64) bf = 0;
    else if (zeros >= 192) bf = 0;
    *flag = bf;
  }
}

// ---------------- K1a/K1b: BN stats (unchanged) ----------------
__global__ __launch_bounds__(256) void k_stats(const void* __restrict__ s, const void* __restrict__ a,
                                               const int* __restrict__ flag, float* __restrict__ part) {
  __shared__ float red[512];
  bool bf = (*flag != 0);
  int tid = threadIdx.x;
  int blk = blockIdx.x;
  int n = blk >> 5, c = blk & 31;
  int b0 = c << 9;
  {
    int f = tid & 63, bsub = tid >> 6;
    size_t base = (size_t)n * BATCH * SD;
    float sum = 0.f, sq = 0.f;
    for (int b = b0 + bsub; b < b0 + 512; b += 4) {
      float x = ldin(s, base + (size_t)b * SD + f, bf);
      sum += x; sq += x * x;
    }
    red[tid] = sum; red[256 + tid] = sq;
  }
  __syncthreads();
  if (tid < 64) {
    float S = red[tid] + red[tid + 64] + red[tid + 128] + red[tid + 192];
    float Q = red[256 + tid] + red[256 + tid + 64] + red[256 + tid + 128] + red[256 + tid + 192];
    float* p = part + ((size_t)blk * IND + tid) * 2;
    p[0] = S; p[1] = Q;
  }
  __syncthreads();
  {
    int f = tid & 15, bsub = tid >> 4;
    size_t base = (size_t)n * BATCH * AD;
    float sum = 0.f, sq = 0.f;
    for (int b = b0 + bsub; b < b0 + 512; b += 16) {
      float x = ldin(a, base + (size_t)b * AD + f, bf);
      sum += x; sq += x * x;
    }
    red[tid] = sum; red[256 + tid] = sq;
  }
  __syncthreads();
  if (tid < 16) {
    float S = 0.f, Q = 0.f;
    for (int g = 0; g < 16; g++) { S += red[g * 16 + tid]; Q += red[256 + g * 16 + tid]; }
    float* p = part + ((size_t)blk * IND + SD + tid) * 2;
    p[0] = S; p[1] = Q;
  }
}

__global__ __launch_bounds__(64) void k_stats_fin(const float* __restrict__ part, float* __restrict__ mr) {
  int i = blockIdx.x * 64 + threadIdx.x;
  if (i >= NA * IND) return;
  int n = i / IND, f = i - n * IND;
  float S = 0.f, Q = 0.f;
  for (int c = 0; c < 32; c++) {
    const float* p = part + ((size_t)(n * 32 + c) * IND + f) * 2;
    S += p[0]; Q += p[1];
  }
  float mean = S * (1.f / BATCH);
  float var = Q * (1.f / BATCH) - mean * mean;
  mr[i * 2] = mean;
  mr[i * 2 + 1] = rsqrtf(var + EPS);
}

// ---------------- K2: encoders (unchanged from round 2, passing) ----------------
__global__ __launch_bounds__(256) void k_enc(const void* __restrict__ s, const void* __restrict__ a,
    const void* __restrict__ Wsa, const void* __restrict__ bsa,
    const void* __restrict__ Wse, const void* __restrict__ bse,
    const float* __restrict__ mr, const int* __restrict__ flag,
    u16* __restrict__ E, u16* __restrict__ SEo) {
  __shared__ float Wf[IND * HID];
  __shared__ float san[64 * SANP];
  __shared__ float mst[IND * 2];
  bool bf = (*flag != 0);
  int tid = threadIdx.x;
  int n = blockIdx.y;
  int b0 = blockIdx.x * 64;
  if (tid < IND * 2) mst[tid] = mr[n * IND * 2 + tid];
  __syncthreads();
  for (int i = tid; i < 64 * IND; i += 256) {
    int r = i / IND, f = i - r * IND;
    float x = (f < SD) ? ldin(s, ((size_t)n * BATCH + b0 + r) * SD + f, bf)
                       : ldin(a, ((size_t)n * BATCH + b0 + r) * AD + (f - SD), bf);
    san[r * SANP + f] = (x - mst[f * 2]) * mst[f * 2 + 1];
  }
  for (int i = tid; i < IND * HID; i += 256) Wf[i] = ldin(Wsa, (size_t)n * IND * HID + i, bf);
  __syncthreads();
  int h2 = tid & 63, bl = tid >> 6;
  {
    float bv0 = ldin(bsa, n * HID + 2 * h2, bf), bv1 = ldin(bsa, n * HID + 2 * h2 + 1, bf);
    float acc0[16], acc1[16];
    #pragma unroll
    for (int r = 0; r < 16; r++) { acc0[r] = bv0; acc1[r] = bv1; }
    for (int k = 0; k < IND; k++) {
      float w0 = Wf[k * HID + 2 * h2], w1 = Wf[k * HID + 2 * h2 + 1];
      #pragma unroll
      for (int r = 0; r < 16; r++) {
        float x = san[(bl * 16 + r) * SANP + k];
        acc0[r] = fmaf(x, w0, acc0[r]);
        acc1[r] = fmaf(x, w1, acc1[r]);
      }
    }
    #pragma unroll
    for (int r = 0; r < 16; r++) {
      int b = b0 + bl * 16 + r;
      ((u32*)E)[((size_t)n * BATCH + b) * (HID / 2) + h2] =
          (u32)f2bf(lrelu(acc0[r])) | ((u32)f2bf(lrelu(acc1[r])) << 16);
    }
  }
  __syncthreads();
  for (int i = tid; i < SD * HID; i += 256) Wf[i] = ldin(Wse, (size_t)n * SD * HID + i, bf);
  __syncthreads();
  {
    float bv0 = ldin(bse, n * HID + 2 * h2, bf), bv1 = ldin(bse, n * HID + 2 * h2 + 1, bf);
    float acc0[16], acc1[16];
    #pragma unroll
    for (int r = 0; r < 16; r++) { acc0[r] = bv0; acc1[r] = bv1; }
    for (int k = 0; k < SD; k++) {
      float w0 = Wf[k * HID + 2 * h2], w1 = Wf[k * HID + 2 * h2 + 1];
      #pragma unroll
      for (int r = 0; r < 16; r++) {
        float x = san[(bl * 16 + r) * SANP + k];
        acc0[r] = fmaf(x, w0, acc0[r]);
        acc1[r] = fmaf(x, w1, acc1[r]);
      }
    }
    #pragma unroll
    for (int r = 0; r < 16; r++) {
      int b = b0 + bl * 16 + r;
      ((u32*)SEo)[((size_t)n * BATCH + b) * (HID / 2) + h2] =
          (u32)f2bf(lrelu(acc0[r])) | ((u32)f2bf(lrelu(acc1[r])) << 16);
    }
  }
}

// ---------------- K3: fused MFMA projections + masked softmax attention ----------------
// block = (head p, 8-batch tile) x ALL 8 agents. M = 64 rows (agent*8 + b).
// sel/keys/vals computed via mfma_f32_16x16x32_bf16 in LDS, consumed in-block.
// LDS: Xt 17408 + Wt 26112 + 3x4352 + lg 2048 + bvf 128 = 58752 B (3 blocks/CU by LDS)
__global__ __launch_bounds__(256) void k_pattn(
    const u16* __restrict__ E, const u16* __restrict__ SEi,
    const void* __restrict__ Wk_g, const void* __restrict__ Wsl_g, const void* __restrict__ Wv_g,
    const void* __restrict__ bv_g, const int* __restrict__ flag, u16* __restrict__ OT) {
  __shared__ __align__(16) u16 Xt[64 * KP];   // SE rows, then E rows (row = agent*8 + b)
  __shared__ __align__(16) u16 Wt[96 * KP];   // transposed weights: cols 0-31 Wsel, 32-63 Wk, 64-95 Wv
  __shared__ u16 selb[64 * SP];
  __shared__ u16 keyb[64 * SP];
  __shared__ u16 valb[64 * SP];
  __shared__ float lg[64 * 8];                // logits/weights [i*8+b][j]
  __shared__ float bvf[ATT];
  bool bf = (*flag != 0);
  int tid = threadIdx.x;
  int p = blockIdx.y;
  int b0 = blockIdx.x * 8;
  int w = tid >> 6, lane = tid & 63, q = lane >> 4, rl = lane & 15;

  // stage Wt[col][k] = W[p][k][d]  (col = mat*32 + d)
  for (int idx = tid; idx < 96 * 128; idx += 256) {
    int k = idx & 127, col = idx >> 7;
    int mat = col >> 5, d = col & 31;
    size_t src = ((size_t)p * HID + k) * ATT + d;
    u16 v = (mat == 0) ? ldbf(Wsl_g, src, bf) : (mat == 1) ? ldbf(Wk_g, src, bf) : ldbf(Wv_g, src, bf);
    Wt[col * KP + k] = v;
  }
  if (tid < ATT) bvf[tid] = ldin(bv_g, p * ATT + tid, bf);
  // stage Xt <- SE rows
  {
    const u32* su = (const u32*)SEi;
    for (int idx = tid; idx < 64 * 64; idx += 256) {
      int row = idx >> 6, c = idx & 63;
      ((u32*)&Xt[row * KP])[c] = su[(((size_t)(row >> 3)) * BATCH + b0 + (row & 7)) * 64 + c];
    }
  }
  __syncthreads();
  // --- SEL = se @ Wsel[p] ---  (wave w -> m-tile w; n-tiles 0..1)
  {
    float4f acs[2] = {};
    #pragma unroll
    for (int kc = 0; kc < 4; kc++) {
      short8 af = *(const short8*)&Xt[(w * 16 + rl) * KP + kc * 32 + q * 8];
      #pragma unroll
      for (int nt = 0; nt < 2; nt++) {
        short8 bb = *(const short8*)&Wt[(nt * 16 + rl) * KP + kc * 32 + q * 8];
        acs[nt] = MFMA16(af, bb, acs[nt]);
      }
    }
    #pragma unroll
    for (int nt = 0; nt < 2; nt++)
      #pragma unroll
      for (int r = 0; r < 4; r++)
        selb[(w * 16 + q * 4 + r) * SP + nt * 16 + rl] = f2bf(acs[nt][r]);
  }
  __syncthreads();
  // restage Xt <- E rows
  {
    const u32* su = (const u32*)E;
    for (int idx = tid; idx < 64 * 64; idx += 256) {
      int row = idx >> 6, c = idx & 63;
      ((u32*)&Xt[row * KP])[c] = su[(((size_t)(row >> 3)) * BATCH + b0 + (row & 7)) * 64 + c];
    }
  }
  __syncthreads();
  // --- KEYS = e @ Wk[p],  VALS = lrelu(e @ Wv[p] + bv[p]) ---
  {
    float4f ack[2] = {}, acv[2] = {};
    #pragma unroll
    for (int kc = 0; kc < 4; kc++) {
      short8 af = *(const short8*)&Xt[(w * 16 + rl) * KP + kc * 32 + q * 8];
      #pragma unroll
      for (int nt = 0; nt < 2; nt++) {
        short8 bk = *(const short8*)&Wt[(32 + nt * 16 + rl) * KP + kc * 32 + q * 8];
        ack[nt] = MFMA16(af, bk, ack[nt]);
        short8 bv8 = *(const short8*)&Wt[(64 + nt * 16 + rl) * KP + kc * 32 + q * 8];
        acv[nt] = MFMA16(af, bv8, acv[nt]);
      }
    }
    #pragma unroll
    for (int nt = 0; nt < 2; nt++)
      #pragma unroll
      for (int r = 0; r < 4; r++) {
        int row = w * 16 + q * 4 + r, d = nt * 16 + rl;
        keyb[row * SP + d] = f2bf(ack[nt][r]);
        valb[row * SP + d] = f2bf(lrelu(acv[nt][r] + bvf[d]));
      }
  }
  __syncthreads();
  // --- logits[i][b][j] = sel_i . key_j / sqrt(32), self-masked ---
  for (int t = tid; t < 512; t += 256) {
    int i = t >> 6, j = (t >> 3) & 7, b = t & 7;
    float lv;
    if (i == j) {
      lv = -1e9f;
    } else {
      const u32* sp = (const u32*)&selb[(i * 8 + b) * SP];
      const u32* kp = (const u32*)&keyb[(j * 8 + b) * SP];
      float acc = 0.f;
      #pragma unroll
      for (int d2 = 0; d2 < 16; d2++) {
        u32 sv = sp[d2], kv = kp[d2];
        acc = fmaf(lo2f(sv), lo2f(kv), acc);
        acc = fmaf(hi2f(sv), hi2f(kv), acc);
      }
      lv = acc * 0.17677669529663687f;
    }
    lg[(i * 8 + b) * 8 + j] = lv;
  }
  __syncthreads();
  // --- softmax over j ---
  if (tid < 64) {
    float* row = &lg[tid * 8];
    float m = row[0];
    #pragma unroll
    for (int j = 1; j < 8; j++) m = fmaxf(m, row[j]);
    float ex[8]; float ssum = 0.f;
    #pragma unroll
    for (int j = 0; j < 8; j++) { ex[j] = __expf(row[j] - m); ssum += ex[j]; }
    float inv = 1.f / ssum;
    #pragma unroll
    for (int j = 0; j < 8; j++) row[j] = ex[j] * inv;
  }
  __syncthreads();
  // --- other[i][b][d] -> OT[i][b][p*32+d] ---
  {
    int i = tid >> 5, d = tid & 31;
    for (int b = 0; b < 8; b++) {
      float acc = 0.f;
      #pragma unroll
      for (int j = 0; j < 8; j++)
        acc = fmaf(lg[(i * 8 + b) * 8 + j], bf2f(valb[(j * 8 + b) * SP + d]), acc);
      OT[((size_t)i * BATCH + b0 + b) * HID + p * ATT + d] = f2bf(acc);
    }
  }
}

// ---------------- K4: critic MFMA GEMM + argmax gather ----------------
// block = agent n x 128 batch rows. h = lrelu([se|other] @ Wc1 + bc1)  (K=256 in 2 phases x 2 k-halves)
// LDS: Xt 34816 + W1t 18432 + bc1f 512 + amax 512 = 54272 B (2 blocks/CU)
__global__ __launch_bounds__(256) void k_critic(
    const u16* __restrict__ SEi, const u16* __restrict__ OT, const void* __restrict__ a_g,
    const void* __restrict__ Wc1_g, const void* __restrict__ bc1_g,
    const void* __restrict__ Wc2_g, const void* __restrict__ bc2_g,
    const int* __restrict__ flag, void* __restrict__ qo) {
  __shared__ __align__(16) u16 Xt[128 * KP];    // input rows; reused as ht (bf16 hidden)
  __shared__ __align__(16) u16 W1t[128 * KP2];  // transposed Wc1 64-k slice; reused as wc2f (f32)
  __shared__ float bc1f[HID];
  __shared__ int amax[128];
  bool bf = (*flag != 0);
  int tid = threadIdx.x;
  int n = blockIdx.y;
  int b0 = blockIdx.x * 128;
  int w = tid >> 6, lane = tid & 63, q = lane >> 4, rl = lane & 15;
  if (tid < HID) bc1f[tid] = ldin(bc1_g, n * HID + tid, bf);

  float4f acc[2][8] = {};   // m-tiles {2w, 2w+1} x n-tiles 0..7
  for (int ph = 0; ph < 2; ph++) {
    // stage Xt rows (full 128-K of this phase)
    const u32* su = (const u32*)(ph == 0 ? SEi : OT);
    for (int idx = tid; idx < 128 * 64; idx += 256) {
      int row = idx >> 6, c = idx & 63;
      ((u32*)&Xt[row * KP])[c] = su[((size_t)n * BATCH + b0 + row) * 64 + c];
    }
    for (int kh = 0; kh < 2; kh++) {
      // stage W1t[col][kk] = Wc1[n][ph*128 + kh*64 + kk][col]
      for (int idx = tid; idx < 128 * 64; idx += 256) {
        int col = idx & 127, kk = idx >> 7;
        W1t[col * KP2 + kk] = ldbf(Wc1_g, ((size_t)n * 2 * HID + ph * HID + kh * 64 + kk) * HID + col, bf);
      }
      __syncthreads();
      #pragma unroll
      for (int kc = 0; kc < 2; kc++) {
        short8 a0 = *(const short8*)&Xt[((2 * w) * 16 + rl) * KP + kh * 64 + kc * 32 + q * 8];
        short8 a1 = *(const short8*)&Xt[((2 * w + 1) * 16 + rl) * KP + kh * 64 + kc * 32 + q * 8];
        #pragma unroll
        for (int nt = 0; nt < 8; nt++) {
          short8 bb = *(const short8*)&W1t[(nt * 16 + rl) * KP2 + kc * 32 + q * 8];
          acc[0][nt] = MFMA16(a0, bb, acc[0][nt]);
          acc[1][nt] = MFMA16(a1, bb, acc[1][nt]);
        }
      }
      __syncthreads();   // before next W1t / Xt restage (and before epilogue reuse)
    }
  }
  // epilogue: ht = lrelu(acc + bc1), bf16, into Xt region
  u16* ht = Xt;
  #pragma unroll
  for (int mi = 0; mi < 2; mi++)
    #pragma unroll
    for (int nt = 0; nt < 8; nt++)
      #pragma unroll
      for (int r = 0; r < 4; r++) {
        int row = (2 * w + mi) * 16 + q * 4 + r, col = nt * 16 + rl;
        ht[row * KP + col] = f2bf(lrelu(acc[mi][nt][r] + bc1f[col]));
      }
  // stage Wc2 (f32) into W1t region; argmax of a
  float* wc2f = (float*)W1t;   // 128*16 f32 = 8192 B
  for (int idx = tid; idx < HID * AD; idx += 256)
    wc2f[idx] = ldin(Wc2_g, (size_t)n * HID * AD + idx, bf);
  if (tid < 128) {
    size_t base = ((size_t)n * BATCH + b0 + tid) * AD;
    float best = ldin(a_g, base, bf); int bi = 0;
    for (int o = 1; o < AD; o++) {
      float v = ldin(a_g, base + o, bf);
      if (v > best) { best = v; bi = o; }   // strict > = first-max (np.argmax)
    }
    amax[tid] = bi;
  }
  __syncthreads();
  {
    int b = tid >> 1, half = tid & 1;
    int col = amax[b];
    float acq = 0.f;
    const u16* hr = &ht[b * KP + half * 64];
    #pragma unroll
    for (int k = 0; k < 64; k++)
      acq = fmaf(bf2f(hr[k]), wc2f[(half * 64 + k) * AD + col], acq);
    acq += __shfl_xor(acq, 1);
    if (half == 0) {
      float v = acq + ldin(bc2_g, n * AD + col, bf);
      size_t oidx = (size_t)n * BATCH + b0 + b;
      if (bf) ((u16*)qo)[oidx] = f2bf(v);
      else    ((float*)qo)[oidx] = v;
    }
  }
}

extern "C" void kernel_launch(void* const* d_in, const int* in_sizes, int n_in,
                              void* d_out, int out_size, void* d_ws, size_t ws_size,
                              hipStream_t stream) {
  const void* s   = d_in[0];
  const void* a   = d_in[1];
  const void* Wsa = d_in[2];
  const void* bsa = d_in[3];
  const void* Wse = d_in[4];
  const void* bse = d_in[5];
  const void* Wk  = d_in[6];
  const void* Wsl = d_in[7];
  const void* Wv  = d_in[8];
  const void* bv  = d_in[9];
  const void* Wc1 = d_in[10];
  const void* bc1 = d_in[11];
  const void* Wc2 = d_in[12];
  const void* bc2 = d_in[13];

  char* ws = (char*)d_ws;
  int*   flag = (int*)ws;
  float* part = (float*)(ws + 256);
  float* mr   = (float*)(ws + 256 + 163840);
  u16* E      = (u16*)(ws + 169216);
  u16* SEb    = (u16*)(ws + 169216 + 33554432ull);
  u16* OT     = (u16*)(ws + 169216 + 2ull * 33554432ull);

  k_detect<<<1, 64, 0, stream>>>((const u32*)s, flag);
  k_stats<<<256, 256, 0, stream>>>(s, a, flag, part);
  k_stats_fin<<<10, 64, 0, stream>>>(part, mr);
  k_enc<<<dim3(BATCH / 64, NA), 256, 0, stream>>>(s, a, Wsa, bsa, Wse, bse, mr, flag, E, SEb);
  k_pattn<<<dim3(BATCH / 8, HEADS), 256, 0, stream>>>(E, SEb, Wk, Wsl, Wv, bv, flag, OT);
  k_critic<<<dim3(BATCH / 128, NA), 256, 0, stream>>>(SEb, OT, a, Wc1, bc1, Wc2, bc2, flag, d_out);
}

// Round 4
// 415.009 us; speedup vs baseline: 3.9624x; 1.8154x over previous
//
#include <hip/hip_runtime.h>

// Attention_Critic on MI355X — round 4: all-MFMA pipeline, head-loop-inside attention,
// pre-transposed weights (k_wprep) for vectorized LDS staging.
//
// ws layout (bytes):
//   [0,256)        int flag (1 = bf16 inputs, 0 = f32)
//   [256,+163840)  stats partials f32 [8][32][80][2]
//   [164096,+5120) mean/rsig f32 [8][80][2]
//   [169216,...)   Wsa_t bf16 [8][128 col][104 k]   (212992 B, k>=80 zero)
//   [382208,...)   Wse_t bf16 [8][128 col][72 k]    (147456 B, k>=64 zero)
//   [529664,...)   Wp_t  bf16 [4 p][3 mat][32 d][136 k] (104448 B, k>=128 zero; mat 0=sel,1=key,2=val)
//   [634112,...)   Wc1t  bf16 [8][128 col][256 k]   (524288 B)
//   [1158400,+32M) E   bf16 [8][16384][128]
//   [+32M,+64M)    SE  bf16 [8][16384][128]
//   [+64M,+96M)    OT  bf16 [8][16384][128]
// total ~97.1 MB.

typedef unsigned short u16;
typedef unsigned int u32;

#define NA 8
#define BATCH 16384
#define SD 64
#define AD 16
#define IND 80
#define HID 128
#define HEADS 4
#define ATT 32
#define EPS 1e-5f
#define KP 136    // u16 row stride for 128-k tiles (272B, 16B-aligned, 2-way banks)
#define KP3 104   // u16 row stride for 96-k tiles (208B, 16B-aligned)
#define KPS 72    // u16 row stride for 64-k tiles (144B, 16B-aligned)
#define SP 34     // row stride for 32-wide sel/key/val LDS tiles

using short8 = __attribute__((ext_vector_type(8))) short;
using float4f = __attribute__((ext_vector_type(4))) float;
#define MFMA16(a, b, c) __builtin_amdgcn_mfma_f32_16x16x32_bf16((a), (b), (c), 0, 0, 0)

__device__ __forceinline__ float bf2f(u16 u) { union { u32 i; float f; } v; v.i = ((u32)u) << 16; return v.f; }
__device__ __forceinline__ float lo2f(u32 w) { union { u32 i; float f; } v; v.i = w << 16; return v.f; }
__device__ __forceinline__ float hi2f(u32 w) { union { u32 i; float f; } v; v.i = w & 0xffff0000u; return v.f; }
__device__ __forceinline__ u16 f2bf(float f) {
  union { float f; u32 i; } v; v.f = f;
  u32 x = v.i;
  x += 0x7fffu + ((x >> 16) & 1u);   // RNE
  return (u16)(x >> 16);
}
__device__ __forceinline__ float lrelu(float x) { return x > 0.f ? x : 0.01f * x; }
__device__ __forceinline__ float ldin(const void* p, size_t i, bool bf) {
  return bf ? bf2f(((const u16*)p)[i]) : ((const float*)p)[i];
}
__device__ __forceinline__ u16 ldbf(const void* p, size_t i, bool bf) {
  return bf ? ((const u16*)p)[i] : f2bf(((const float*)p)[i]);
}

// ---------------- K0: input dtype detection (unchanged, proven) ----------------
__global__ __launch_bounds__(64) void k_detect(const u32* __restrict__ s, int* __restrict__ flag) {
  int t = threadIdx.x;
  int insane = 0, zeros = 0;
  for (int i = t; i < 256; i += 64) {
    u32 lo = s[i] & 0xffffu;
    u32 e = (lo >> 7) & 0xffu;
    if (lo == 0u || lo == 0x8000u) zeros++;
    else if (e < 0x70u || e > 0x8fu) insane++;
  }
  for (int o = 32; o; o >>= 1) { insane += __shfl_down(insane, o); zeros += __shfl_down(zeros, o); }
  if (t == 0) {
    int bf = 1;
    if (insane >= 64) bf = 0;
    else if (zeros >= 192) bf = 0;
    *flag = bf;
  }
}

// ---------------- K1a/K1b: BN stats (unchanged, proven) ----------------
__global__ __launch_bounds__(256) void k_stats(const void* __restrict__ s, const void* __restrict__ a,
                                               const int* __restrict__ flag, float* __restrict__ part) {
  __shared__ float red[512];
  bool bf = (*flag != 0);
  int tid = threadIdx.x;
  int blk = blockIdx.x;
  int n = blk >> 5, c = blk & 31;
  int b0 = c << 9;
  {
    int f = tid & 63, bsub = tid >> 6;
    size_t base = (size_t)n * BATCH * SD;
    float sum = 0.f, sq = 0.f;
    for (int b = b0 + bsub; b < b0 + 512; b += 4) {
      float x = ldin(s, base + (size_t)b * SD + f, bf);
      sum += x; sq += x * x;
    }
    red[tid] = sum; red[256 + tid] = sq;
  }
  __syncthreads();
  if (tid < 64) {
    float S = red[tid] + red[tid + 64] + red[tid + 128] + red[tid + 192];
    float Q = red[256 + tid] + red[256 + tid + 64] + red[256 + tid + 128] + red[256 + tid + 192];
    float* p = part + ((size_t)blk * IND + tid) * 2;
    p[0] = S; p[1] = Q;
  }
  __syncthreads();
  {
    int f = tid & 15, bsub = tid >> 4;
    size_t base = (size_t)n * BATCH * AD;
    float sum = 0.f, sq = 0.f;
    for (int b = b0 + bsub; b < b0 + 512; b += 16) {
      float x = ldin(a, base + (size_t)b * AD + f, bf);
      sum += x; sq += x * x;
    }
    red[tid] = sum; red[256 + tid] = sq;
  }
  __syncthreads();
  if (tid < 16) {
    float S = 0.f, Q = 0.f;
    for (int g = 0; g < 16; g++) { S += red[g * 16 + tid]; Q += red[256 + g * 16 + tid]; }
    float* p = part + ((size_t)blk * IND + SD + tid) * 2;
    p[0] = S; p[1] = Q;
  }
}

__global__ __launch_bounds__(64) void k_stats_fin(const float* __restrict__ part, float* __restrict__ mr) {
  int i = blockIdx.x * 64 + threadIdx.x;
  if (i >= NA * IND) return;
  int n = i / IND, f = i - n * IND;
  float S = 0.f, Q = 0.f;
  for (int c = 0; c < 32; c++) {
    const float* p = part + ((size_t)(n * 32 + c) * IND + f) * 2;
    S += p[0]; Q += p[1];
  }
  float mean = S * (1.f / BATCH);
  float var = Q * (1.f / BATCH) - mean * mean;
  mr[i * 2] = mean;
  mr[i * 2 + 1] = rsqrtf(var + EPS);
}

// ---------------- K2: weight prep — transpose+pad all GEMM weights to bf16 B-layout ----------------
#define A1 (NA * HID * KP3)          // Wsa_t  106496
#define A2 (NA * HID * KPS)          // Wse_t   73728
#define A3 (HEADS * 3 * ATT * KP)    // Wp_t    52224
#define A4 (NA * HID * 256)          // Wc1t   262144
__global__ __launch_bounds__(256) void k_wprep(
    const void* __restrict__ Wsa, const void* __restrict__ Wse,
    const void* __restrict__ Wsl, const void* __restrict__ Wk, const void* __restrict__ Wv,
    const void* __restrict__ Wc1, const int* __restrict__ flag,
    u16* __restrict__ Wsa_t, u16* __restrict__ Wse_t, u16* __restrict__ Wp_t, u16* __restrict__ Wc1t) {
  bool bf = (*flag != 0);
  int i = blockIdx.x * 256 + threadIdx.x;
  if (i < A1) {
    int n = i / (HID * KP3), r = i % (HID * KP3), col = r / KP3, k = r % KP3;
    Wsa_t[i] = (k < IND) ? ldbf(Wsa, ((size_t)n * IND + k) * HID + col, bf) : (u16)0;
  } else if (i < A1 + A2) {
    int j = i - A1;
    int n = j / (HID * KPS), r = j % (HID * KPS), col = r / KPS, k = r % KPS;
    Wse_t[j] = (k < SD) ? ldbf(Wse, ((size_t)n * SD + k) * HID + col, bf) : (u16)0;
  } else if (i < A1 + A2 + A3) {
    int j = i - A1 - A2;
    int pm = j / (ATT * KP), r = j % (ATT * KP), d = r / KP, k = r % KP;
    int p = pm / 3, mat = pm % 3;
    u16 v = 0;
    if (k < HID) {
      size_t src = ((size_t)p * HID + k) * ATT + d;
      v = (mat == 0) ? ldbf(Wsl, src, bf) : (mat == 1) ? ldbf(Wk, src, bf) : ldbf(Wv, src, bf);
    }
    Wp_t[j] = v;
  } else {
    int j = i - A1 - A2 - A3;
    if (j < A4) {
      int n = j / (HID * 256), r = j % (HID * 256), col = r / 256, k = r % 256;
      Wc1t[j] = ldbf(Wc1, ((size_t)n * 2 * HID + k) * HID + col, bf);
    }
  }
}

// ---------------- K3: MFMA encoders  E = lrelu(bn(sa)@Wsa+b), SE = lrelu(bn(s)@Wse+b) ----------------
// block = 1 agent x 128 batch rows. LDS: sanb 26624 + Wt 26624 + mst 640 + biases 1024 = 54912 B
__global__ __launch_bounds__(256) void k_enc2(const void* __restrict__ s, const void* __restrict__ a,
    const u16* __restrict__ Wsa_t, const void* __restrict__ bsa,
    const u16* __restrict__ Wse_t, const void* __restrict__ bse,
    const float* __restrict__ mr, const int* __restrict__ flag,
    u16* __restrict__ E, u16* __restrict__ SEo) {
  __shared__ __align__(16) u16 sanb[128 * KP3];
  __shared__ __align__(16) u16 Wt[128 * KP3];
  __shared__ float mst[IND * 2];
  __shared__ float bsaf[HID], bsef[HID];
  bool bf = (*flag != 0);
  int tid = threadIdx.x;
  int n = blockIdx.y;
  int b0 = blockIdx.x * 128;
  int w = tid >> 6, lane = tid & 63, q = lane >> 4, rl = lane & 15;
  if (tid < IND * 2) mst[tid] = mr[n * IND * 2 + tid];
  if (tid < HID) { bsaf[tid] = ldin(bsa, n * HID + tid, bf); bsef[tid] = ldin(bse, n * HID + tid, bf); }
  __syncthreads();
  // stage normalized rows (bf16): k<64 from s, 64..80 from a, 80..104 zero
  for (int idx = tid; idx < 128 * KP3; idx += 256) {
    int row = idx / KP3, k = idx - row * KP3;
    u16 v = 0;
    if (k < SD) {
      float x = ldin(s, ((size_t)n * BATCH + b0 + row) * SD + k, bf);
      v = f2bf((x - mst[k * 2]) * mst[k * 2 + 1]);
    } else if (k < IND) {
      float x = ldin(a, ((size_t)n * BATCH + b0 + row) * AD + (k - SD), bf);
      v = f2bf((x - mst[k * 2]) * mst[k * 2 + 1]);
    }
    sanb[idx] = v;
  }
  // stage Wsa_t (flat copy, zero-padded already)
  {
    const u32* src = (const u32*)(Wsa_t + (size_t)n * HID * KP3);
    u32* dst = (u32*)Wt;
    for (int idx = tid; idx < HID * KP3 / 2; idx += 256) dst[idx] = src[idx];
  }
  __syncthreads();
  // E GEMM: K=96 (3 k-steps), per wave m-tiles {2w,2w+1}, n-tiles 0..7
  {
    float4f acc[2][8] = {};
    #pragma unroll
    for (int kc = 0; kc < 3; kc++) {
      short8 a0 = *(const short8*)&sanb[((2 * w) * 16 + rl) * KP3 + kc * 32 + q * 8];
      short8 a1 = *(const short8*)&sanb[((2 * w + 1) * 16 + rl) * KP3 + kc * 32 + q * 8];
      #pragma unroll
      for (int nt = 0; nt < 8; nt++) {
        short8 bb = *(const short8*)&Wt[(nt * 16 + rl) * KP3 + kc * 32 + q * 8];
        acc[0][nt] = MFMA16(a0, bb, acc[0][nt]);
        acc[1][nt] = MFMA16(a1, bb, acc[1][nt]);
      }
    }
    #pragma unroll
    for (int mi = 0; mi < 2; mi++)
      #pragma unroll
      for (int nt = 0; nt < 8; nt++)
        #pragma unroll
        for (int r = 0; r < 4; r++) {
          int row = (2 * w + mi) * 16 + q * 4 + r, col = nt * 16 + rl;
          E[((size_t)n * BATCH + b0 + row) * HID + col] = f2bf(lrelu(acc[mi][nt][r] + bsaf[col]));
        }
  }
  __syncthreads();
  // stage Wse_t and run SE GEMM: K=64 (2 k-steps), row stride KPS
  {
    const u32* src = (const u32*)(Wse_t + (size_t)n * HID * KPS);
    u32* dst = (u32*)Wt;
    for (int idx = tid; idx < HID * KPS / 2; idx += 256) dst[idx] = src[idx];
  }
  __syncthreads();
  {
    float4f acc[2][8] = {};
    #pragma unroll
    for (int kc = 0; kc < 2; kc++) {
      short8 a0 = *(const short8*)&sanb[((2 * w) * 16 + rl) * KP3 + kc * 32 + q * 8];
      short8 a1 = *(const short8*)&sanb[((2 * w + 1) * 16 + rl) * KP3 + kc * 32 + q * 8];
      #pragma unroll
      for (int nt = 0; nt < 8; nt++) {
        short8 bb = *(const short8*)&Wt[(nt * 16 + rl) * KPS + kc * 32 + q * 8];
        acc[0][nt] = MFMA16(a0, bb, acc[0][nt]);
        acc[1][nt] = MFMA16(a1, bb, acc[1][nt]);
      }
    }
    #pragma unroll
    for (int mi = 0; mi < 2; mi++)
      #pragma unroll
      for (int nt = 0; nt < 8; nt++)
        #pragma unroll
        for (int r = 0; r < 4; r++) {
          int row = (2 * w + mi) * 16 + q * 4 + r, col = nt * 16 + rl;
          SEo[((size_t)n * BATCH + b0 + row) * HID + col] = f2bf(lrelu(acc[mi][nt][r] + bsef[col]));
        }
  }
}

// ---------------- K4: fused projections + attention, head loop inside ----------------
// block = 8 batch x 8 agents (M=64 rows). X staged once per source (SE then E).
// LDS: X 17408 + Wh 17408 + selb 17408 + keyb 4352 + valb 4352 + lg 2048 + bvf 512 = 63488 B
__global__ __launch_bounds__(256) void k_pattn2(
    const u16* __restrict__ E, const u16* __restrict__ SEi,
    const u16* __restrict__ Wp_t, const void* __restrict__ bv_g,
    const int* __restrict__ flag, u16* __restrict__ OT) {
  __shared__ __align__(16) u16 X[64 * KP];          // rows: n*8 + b
  __shared__ __align__(16) u16 Wh[64 * KP];         // phase1: sel W (rows 0..31); phase2: key|val W
  __shared__ u16 selb[HEADS * 64 * SP];
  __shared__ u16 keyb[64 * SP];
  __shared__ u16 valb[64 * SP];
  __shared__ float lg[64 * 8];
  __shared__ float bvf[HID];
  bool bf = (*flag != 0);
  int tid = threadIdx.x;
  int b0 = blockIdx.x * 8;
  int w = tid >> 6, lane = tid & 63, q = lane >> 4, rl = lane & 15;

  if (tid < HID) bvf[tid] = ldin(bv_g, tid, bf);   // [p*32+d]
  // stage X <- SE
  {
    const u32* su = (const u32*)SEi;
    for (int idx = tid; idx < 64 * 64; idx += 256) {
      int row = idx >> 6, c = idx & 63;
      ((u32*)&X[row * KP])[c] = su[(((size_t)(row >> 3)) * BATCH + b0 + (row & 7)) * 64 + c];
    }
  }
  __syncthreads();
  // ---- phase 1: sel for all heads ----
  for (int p = 0; p < HEADS; p++) {
    {
      const u32* src = (const u32*)(Wp_t + (size_t)(p * 3) * ATT * KP);
      u32* dst = (u32*)Wh;
      for (int idx = tid; idx < ATT * KP / 2; idx += 256) dst[idx] = src[idx];
    }
    __syncthreads();
    {
      float4f acs[2] = {};
      #pragma unroll
      for (int kc = 0; kc < 4; kc++) {
        short8 af = *(const short8*)&X[(w * 16 + rl) * KP + kc * 32 + q * 8];
        #pragma unroll
        for (int nt = 0; nt < 2; nt++) {
          short8 bb = *(const short8*)&Wh[(nt * 16 + rl) * KP + kc * 32 + q * 8];
          acs[nt] = MFMA16(af, bb, acs[nt]);
        }
      }
      #pragma unroll
      for (int nt = 0; nt < 2; nt++)
        #pragma unroll
        for (int r = 0; r < 4; r++)
          selb[(p * 64 + w * 16 + q * 4 + r) * SP + nt * 16 + rl] = f2bf(acs[nt][r]);
    }
    __syncthreads();
  }
  // restage X <- E
  {
    const u32* su = (const u32*)E;
    for (int idx = tid; idx < 64 * 64; idx += 256) {
      int row = idx >> 6, c = idx & 63;
      ((u32*)&X[row * KP])[c] = su[(((size_t)(row >> 3)) * BATCH + b0 + (row & 7)) * 64 + c];
    }
  }
  __syncthreads();
  // ---- phase 2: per head keys+vals, logits, softmax, weighted sum ----
  for (int p = 0; p < HEADS; p++) {
    {
      const u32* src = (const u32*)(Wp_t + (size_t)(p * 3 + 1) * ATT * KP);   // key||val contiguous
      u32* dst = (u32*)Wh;
      for (int idx = tid; idx < 2 * ATT * KP / 2; idx += 256) dst[idx] = src[idx];
    }
    __syncthreads();
    {
      float4f ak[2] = {}, av[2] = {};
      #pragma unroll
      for (int kc = 0; kc < 4; kc++) {
        short8 af = *(const short8*)&X[(w * 16 + rl) * KP + kc * 32 + q * 8];
        #pragma unroll
        for (int nt = 0; nt < 2; nt++) {
          short8 bk = *(const short8*)&Wh[(nt * 16 + rl) * KP + kc * 32 + q * 8];
          ak[nt] = MFMA16(af, bk, ak[nt]);
          short8 bv8 = *(const short8*)&Wh[((2 + nt) * 16 + rl) * KP + kc * 32 + q * 8];
          av[nt] = MFMA16(af, bv8, av[nt]);
        }
      }
      #pragma unroll
      for (int nt = 0; nt < 2; nt++)
        #pragma unroll
        for (int r = 0; r < 4; r++) {
          int row = w * 16 + q * 4 + r, d = nt * 16 + rl;
          keyb[row * SP + d] = f2bf(ak[nt][r]);
          valb[row * SP + d] = f2bf(lrelu(av[nt][r] + bvf[p * ATT + d]));
        }
    }
    __syncthreads();
    // logits[i][b][j] = sel_i . key_j / sqrt(32), self-masked
    for (int t = tid; t < 512; t += 256) {
      int i = t >> 6, j = (t >> 3) & 7, b = t & 7;
      float lv;
      if (i == j) {
        lv = -1e9f;
      } else {
        const u32* sp = (const u32*)&selb[(p * 64 + i * 8 + b) * SP];
        const u32* kp = (const u32*)&keyb[(j * 8 + b) * SP];
        float acc = 0.f;
        #pragma unroll
        for (int d2 = 0; d2 < 16; d2++) {
          u32 sv = sp[d2], kv = kp[d2];
          acc = fmaf(lo2f(sv), lo2f(kv), acc);
          acc = fmaf(hi2f(sv), hi2f(kv), acc);
        }
        lv = acc * 0.17677669529663687f;
      }
      lg[(i * 8 + b) * 8 + j] = lv;
    }
    __syncthreads();
    if (tid < 64) {
      float* row = &lg[tid * 8];
      float m = row[0];
      #pragma unroll
      for (int j = 1; j < 8; j++) m = fmaxf(m, row[j]);
      float ex[8]; float ssum = 0.f;
      #pragma unroll
      for (int j = 0; j < 8; j++) { ex[j] = __expf(row[j] - m); ssum += ex[j]; }
      float inv = 1.f / ssum;
      #pragma unroll
      for (int j = 0; j < 8; j++) row[j] = ex[j] * inv;
    }
    __syncthreads();
    {
      int i = tid >> 5, d = tid & 31;
      for (int b = 0; b < 8; b++) {
        float acc = 0.f;
        #pragma unroll
        for (int j = 0; j < 8; j++)
          acc = fmaf(lg[(i * 8 + b) * 8 + j], bf2f(valb[(j * 8 + b) * SP + d]), acc);
        OT[((size_t)i * BATCH + b0 + b) * HID + p * ATT + d] = f2bf(acc);
      }
    }
    __syncthreads();   // protect Wh/keyb/valb/lg for next head
  }
}

// ---------------- K5: critic MFMA GEMM + argmax gather ----------------
// block = agent x 128 rows. Wc1 staged from pre-transposed Wc1t (vectorized).
// LDS: Xt 34816 + W1t 18432 + bc1f 512 + amax 512 = 54272 B
__global__ __launch_bounds__(256) void k_critic(
    const u16* __restrict__ SEi, const u16* __restrict__ OT, const void* __restrict__ a_g,
    const u16* __restrict__ Wc1t, const void* __restrict__ bc1_g,
    const void* __restrict__ Wc2_g, const void* __restrict__ bc2_g,
    const int* __restrict__ flag, void* __restrict__ qo) {
  __shared__ __align__(16) u16 Xt[128 * KP];    // input rows; reused as ht
  __shared__ __align__(16) u16 W1t[128 * KPS];  // 64-k slice of Wc1t; reused as wc2f (f32)
  __shared__ float bc1f[HID];
  __shared__ int amax[128];
  bool bf = (*flag != 0);
  int tid = threadIdx.x;
  int n = blockIdx.y;
  int b0 = blockIdx.x * 128;
  int w = tid >> 6, lane = tid & 63, q = lane >> 4, rl = lane & 15;
  if (tid < HID) bc1f[tid] = ldin(bc1_g, n * HID + tid, bf);

  float4f acc[2][8] = {};
  for (int ph = 0; ph < 2; ph++) {
    const u32* su = (const u32*)(ph == 0 ? SEi : OT);
    for (int idx = tid; idx < 128 * 64; idx += 256) {
      int row = idx >> 6, c = idx & 63;
      ((u32*)&Xt[row * KP])[c] = su[((size_t)n * BATCH + b0 + row) * 64 + c];
    }
    for (int kh = 0; kh < 2; kh++) {
      // stage W1t[col][0..63] <- Wc1t[n][col][ph*128+kh*64 ...]  (vector u32, conflict-free)
      for (int idx = tid; idx < 128 * 32; idx += 256) {
        int col = idx >> 5, kk2 = idx & 31;
        ((u32*)&W1t[col * KPS])[kk2] =
            ((const u32*)(Wc1t + ((size_t)n * HID + col) * 256 + ph * HID + kh * 64))[kk2];
      }
      __syncthreads();
      #pragma unroll
      for (int kc = 0; kc < 2; kc++) {
        short8 a0 = *(const short8*)&Xt[((2 * w) * 16 + rl) * KP + kh * 64 + kc * 32 + q * 8];
        short8 a1 = *(const short8*)&Xt[((2 * w + 1) * 16 + rl) * KP + kh * 64 + kc * 32 + q * 8];
        #pragma unroll
        for (int nt = 0; nt < 8; nt++) {
          short8 bb = *(const short8*)&W1t[(nt * 16 + rl) * KPS + kc * 32 + q * 8];
          acc[0][nt] = MFMA16(a0, bb, acc[0][nt]);
          acc[1][nt] = MFMA16(a1, bb, acc[1][nt]);
        }
      }
      __syncthreads();
    }
  }
  // epilogue: ht = lrelu(acc + bc1) -> Xt region (bf16)
  u16* ht = Xt;
  #pragma unroll
  for (int mi = 0; mi < 2; mi++)
    #pragma unroll
    for (int nt = 0; nt < 8; nt++)
      #pragma unroll
      for (int r = 0; r < 4; r++) {
        int row = (2 * w + mi) * 16 + q * 4 + r, col = nt * 16 + rl;
        ht[row * KP + col] = f2bf(lrelu(acc[mi][nt][r] + bc1f[col]));
      }
  float* wc2f = (float*)W1t;
  for (int idx = tid; idx < HID * AD; idx += 256)
    wc2f[idx] = ldin(Wc2_g, (size_t)n * HID * AD + idx, bf);
  if (tid < 128) {
    size_t base = ((size_t)n * BATCH + b0 + tid) * AD;
    float best = ldin(a_g, base, bf); int bi = 0;
    for (int o = 1; o < AD; o++) {
      float v = ldin(a_g, base + o, bf);
      if (v > best) { best = v; bi = o; }   // strict > = first-max
    }
    amax[tid] = bi;
  }
  __syncthreads();
  {
    int b = tid >> 1, half = tid & 1;
    int col = amax[b];
    float acq = 0.f;
    const u16* hr = &ht[b * KP + half * 64];
    #pragma unroll
    for (int k = 0; k < 64; k++)
      acq = fmaf(bf2f(hr[k]), wc2f[(half * 64 + k) * AD + col], acq);
    acq += __shfl_xor(acq, 1);
    if (half == 0) {
      float v = acq + ldin(bc2_g, n * AD + col, bf);
      size_t oidx = (size_t)n * BATCH + b0 + b;
      if (bf) ((u16*)qo)[oidx] = f2bf(v);
      else    ((float*)qo)[oidx] = v;
    }
  }
}

extern "C" void kernel_launch(void* const* d_in, const int* in_sizes, int n_in,
                              void* d_out, int out_size, void* d_ws, size_t ws_size,
                              hipStream_t stream) {
  const void* s   = d_in[0];
  const void* a   = d_in[1];
  const void* Wsa = d_in[2];
  const void* bsa = d_in[3];
  const void* Wse = d_in[4];
  const void* bse = d_in[5];
  const void* Wk  = d_in[6];
  const void* Wsl = d_in[7];
  const void* Wv  = d_in[8];
  const void* bv  = d_in[9];
  const void* Wc1 = d_in[10];
  const void* bc1 = d_in[11];
  const void* Wc2 = d_in[12];
  const void* bc2 = d_in[13];

  char* ws = (char*)d_ws;
  int*   flag  = (int*)ws;
  float* part  = (float*)(ws + 256);
  float* mr    = (float*)(ws + 164096);
  u16*   Wsa_t = (u16*)(ws + 169216);
  u16*   Wse_t = (u16*)(ws + 382208);
  u16*   Wp_t  = (u16*)(ws + 529664);
  u16*   Wc1t  = (u16*)(ws + 634112);
  u16*   E     = (u16*)(ws + 1158400);
  u16*   SEb   = (u16*)(ws + 1158400 + 33554432ull);
  u16*   OT    = (u16*)(ws + 1158400 + 2ull * 33554432ull);

  k_detect<<<1, 64, 0, stream>>>((const u32*)s, flag);
  k_stats<<<256, 256, 0, stream>>>(s, a, flag, part);
  k_stats_fin<<<10, 64, 0, stream>>>(part, mr);
  k_wprep<<<(A1 + A2 + A3 + A4 + 255) / 256, 256, 0, stream>>>(
      Wsa, Wse, Wsl, Wk, Wv, Wc1, flag, Wsa_t, Wse_t, Wp_t, Wc1t);
  k_enc2<<<dim3(BATCH / 128, NA), 256, 0, stream>>>(s, a, Wsa_t, bsa, Wse_t, bse, mr, flag, E, SEb);
  k_pattn2<<<BATCH / 8, 256, 0, stream>>>(E, SEb, Wp_t, bv, flag, OT);
  k_critic<<<dim3(BATCH / 128, NA), 256, 0, stream>>>(SEb, OT, a, Wc1t, bc1, Wc2, bc2, flag, d_out);
}

// Round 5
// 391.898 us; speedup vs baseline: 4.1961x; 1.0590x over previous
//
#include <hip/hip_runtime.h>

// Attention_Critic on MI355X — round 5: MFMA attention core (logits + weighted sum),
// register softmax via shfl. Everything else carried from round 4 (passing).
//
// ws layout (bytes):
//   [0,256)        int flag (1 = bf16 inputs, 0 = f32)
//   [256,+163840)  stats partials f32 [8][32][80][2]
//   [164096,+5120) mean/rsig f32 [8][80][2]
//   [169216,...)   Wsa_t bf16 [8][128 col][104 k]
//   [382208,...)   Wse_t bf16 [8][128 col][72 k]
//   [529664,...)   Wp_t  bf16 [4 p][3 mat][32 d][136 k]  (mat 0=sel,1=key,2=val)
//   [634112,...)   Wc1t  bf16 [8][128 col][256 k]
//   [1158400,+32M) E   bf16 [8][16384][128]
//   [+32M,+64M)    SE  bf16 [8][16384][128]
//   [+64M,+96M)    OT  bf16 [8][16384][128]

typedef unsigned short u16;
typedef unsigned int u32;

#define NA 8
#define BATCH 16384
#define SD 64
#define AD 16
#define IND 80
#define HID 128
#define HEADS 4
#define ATT 32
#define EPS 1e-5f
#define KP 136    // u16 stride, 128-k tiles (272B: 16B-aligned, 2-way banks)
#define KP3 104   // u16 stride, 96-k tiles
#define KPS 72    // u16 stride, 64-k tiles
#define SP 34     // u16 stride for 32-wide sel/key tiles (68B rows, 4B-aligned reads)
#define VTS 68    // u16 stride for valt [32 d][64 row'] tiles
#define WBS 24    // u16 stride for per-wave softmax weight tiles (48B rows, 16B-aligned)

using short8 = __attribute__((ext_vector_type(8))) short;
using float4f = __attribute__((ext_vector_type(4))) float;
#define MFMA16(a, b, c) __builtin_amdgcn_mfma_f32_16x16x32_bf16((a), (b), (c), 0, 0, 0)

__device__ __forceinline__ float bf2f(u16 u) { union { u32 i; float f; } v; v.i = ((u32)u) << 16; return v.f; }
__device__ __forceinline__ u16 f2bf(float f) {
  union { float f; u32 i; } v; v.f = f;
  u32 x = v.i;
  x += 0x7fffu + ((x >> 16) & 1u);   // RNE
  return (u16)(x >> 16);
}
__device__ __forceinline__ float lrelu(float x) { return x > 0.f ? x : 0.01f * x; }
__device__ __forceinline__ float ldin(const void* p, size_t i, bool bf) {
  return bf ? bf2f(((const u16*)p)[i]) : ((const float*)p)[i];
}
__device__ __forceinline__ u16 ldbf(const void* p, size_t i, bool bf) {
  return bf ? ((const u16*)p)[i] : f2bf(((const float*)p)[i]);
}
// 16B LDS load from a 4B-aligned address (compiler splits into b32/b64 reads)
__device__ __forceinline__ short8 lds_s8(const u16* p) {
  union { short8 v; u32 u[4]; } t;
  const u32* q = (const u32*)p;
  t.u[0] = q[0]; t.u[1] = q[1]; t.u[2] = q[2]; t.u[3] = q[3];
  return t.v;
}

// ---------------- K0: input dtype detection (proven) ----------------
__global__ __launch_bounds__(64) void k_detect(const u32* __restrict__ s, int* __restrict__ flag) {
  int t = threadIdx.x;
  int insane = 0, zeros = 0;
  for (int i = t; i < 256; i += 64) {
    u32 lo = s[i] & 0xffffu;
    u32 e = (lo >> 7) & 0xffu;
    if (lo == 0u || lo == 0x8000u) zeros++;
    else if (e < 0x70u || e > 0x8fu) insane++;
  }
  for (int o = 32; o; o >>= 1) { insane += __shfl_down(insane, o); zeros += __shfl_down(zeros, o); }
  if (t == 0) {
    int bf = 1;
    if (insane >= 64) bf = 0;
    else if (zeros >= 192) bf = 0;
    *flag = bf;
  }
}

// ---------------- K1a/K1b: BN stats (proven) ----------------
__global__ __launch_bounds__(256) void k_stats(const void* __restrict__ s, const void* __restrict__ a,
                                               const int* __restrict__ flag, float* __restrict__ part) {
  __shared__ float red[512];
  bool bf = (*flag != 0);
  int tid = threadIdx.x;
  int blk = blockIdx.x;
  int n = blk >> 5, c = blk & 31;
  int b0 = c << 9;
  {
    int f = tid & 63, bsub = tid >> 6;
    size_t base = (size_t)n * BATCH * SD;
    float sum = 0.f, sq = 0.f;
    for (int b = b0 + bsub; b < b0 + 512; b += 4) {
      float x = ldin(s, base + (size_t)b * SD + f, bf);
      sum += x; sq += x * x;
    }
    red[tid] = sum; red[256 + tid] = sq;
  }
  __syncthreads();
  if (tid < 64) {
    float S = red[tid] + red[tid + 64] + red[tid + 128] + red[tid + 192];
    float Q = red[256 + tid] + red[256 + tid + 64] + red[256 + tid + 128] + red[256 + tid + 192];
    float* p = part + ((size_t)blk * IND + tid) * 2;
    p[0] = S; p[1] = Q;
  }
  __syncthreads();
  {
    int f = tid & 15, bsub = tid >> 4;
    size_t base = (size_t)n * BATCH * AD;
    float sum = 0.f, sq = 0.f;
    for (int b = b0 + bsub; b < b0 + 512; b += 16) {
      float x = ldin(a, base + (size_t)b * AD + f, bf);
      sum += x; sq += x * x;
    }
    red[tid] = sum; red[256 + tid] = sq;
  }
  __syncthreads();
  if (tid < 16) {
    float S = 0.f, Q = 0.f;
    for (int g = 0; g < 16; g++) { S += red[g * 16 + tid]; Q += red[256 + g * 16 + tid]; }
    float* p = part + ((size_t)blk * IND + SD + tid) * 2;
    p[0] = S; p[1] = Q;
  }
}

__global__ __launch_bounds__(64) void k_stats_fin(const float* __restrict__ part, float* __restrict__ mr) {
  int i = blockIdx.x * 64 + threadIdx.x;
  if (i >= NA * IND) return;
  int n = i / IND, f = i - n * IND;
  float S = 0.f, Q = 0.f;
  for (int c = 0; c < 32; c++) {
    const float* p = part + ((size_t)(n * 32 + c) * IND + f) * 2;
    S += p[0]; Q += p[1];
  }
  float mean = S * (1.f / BATCH);
  float var = Q * (1.f / BATCH) - mean * mean;
  mr[i * 2] = mean;
  mr[i * 2 + 1] = rsqrtf(var + EPS);
}

// ---------------- K2: weight prep (proven) ----------------
#define A1 (NA * HID * KP3)
#define A2 (NA * HID * KPS)
#define A3 (HEADS * 3 * ATT * KP)
#define A4 (NA * HID * 256)
__global__ __launch_bounds__(256) void k_wprep(
    const void* __restrict__ Wsa, const void* __restrict__ Wse,
    const void* __restrict__ Wsl, const void* __restrict__ Wk, const void* __restrict__ Wv,
    const void* __restrict__ Wc1, const int* __restrict__ flag,
    u16* __restrict__ Wsa_t, u16* __restrict__ Wse_t, u16* __restrict__ Wp_t, u16* __restrict__ Wc1t) {
  bool bf = (*flag != 0);
  int i = blockIdx.x * 256 + threadIdx.x;
  if (i < A1) {
    int n = i / (HID * KP3), r = i % (HID * KP3), col = r / KP3, k = r % KP3;
    Wsa_t[i] = (k < IND) ? ldbf(Wsa, ((size_t)n * IND + k) * HID + col, bf) : (u16)0;
  } else if (i < A1 + A2) {
    int j = i - A1;
    int n = j / (HID * KPS), r = j % (HID * KPS), col = r / KPS, k = r % KPS;
    Wse_t[j] = (k < SD) ? ldbf(Wse, ((size_t)n * SD + k) * HID + col, bf) : (u16)0;
  } else if (i < A1 + A2 + A3) {
    int j = i - A1 - A2;
    int pm = j / (ATT * KP), r = j % (ATT * KP), d = r / KP, k = r % KP;
    int p = pm / 3, mat = pm % 3;
    u16 v = 0;
    if (k < HID) {
      size_t src = ((size_t)p * HID + k) * ATT + d;
      v = (mat == 0) ? ldbf(Wsl, src, bf) : (mat == 1) ? ldbf(Wk, src, bf) : ldbf(Wv, src, bf);
    }
    Wp_t[j] = v;
  } else {
    int j = i - A1 - A2 - A3;
    if (j < A4) {
      int n = j / (HID * 256), r = j % (HID * 256), col = r / 256, k = r % 256;
      Wc1t[j] = ldbf(Wc1, ((size_t)n * 2 * HID + k) * HID + col, bf);
    }
  }
}

// ---------------- K3: MFMA encoders (proven) ----------------
__global__ __launch_bounds__(256) void k_enc2(const void* __restrict__ s, const void* __restrict__ a,
    const u16* __restrict__ Wsa_t, const void* __restrict__ bsa,
    const u16* __restrict__ Wse_t, const void* __restrict__ bse,
    const float* __restrict__ mr, const int* __restrict__ flag,
    u16* __restrict__ E, u16* __restrict__ SEo) {
  __shared__ __align__(16) u16 sanb[128 * KP3];
  __shared__ __align__(16) u16 Wt[128 * KP3];
  __shared__ float mst[IND * 2];
  __shared__ float bsaf[HID], bsef[HID];
  bool bf = (*flag != 0);
  int tid = threadIdx.x;
  int n = blockIdx.y;
  int b0 = blockIdx.x * 128;
  int w = tid >> 6, lane = tid & 63, q = lane >> 4, rl = lane & 15;
  if (tid < IND * 2) mst[tid] = mr[n * IND * 2 + tid];
  if (tid < HID) { bsaf[tid] = ldin(bsa, n * HID + tid, bf); bsef[tid] = ldin(bse, n * HID + tid, bf); }
  __syncthreads();
  for (int idx = tid; idx < 128 * KP3; idx += 256) {
    int row = idx / KP3, k = idx - row * KP3;
    u16 v = 0;
    if (k < SD) {
      float x = ldin(s, ((size_t)n * BATCH + b0 + row) * SD + k, bf);
      v = f2bf((x - mst[k * 2]) * mst[k * 2 + 1]);
    } else if (k < IND) {
      float x = ldin(a, ((size_t)n * BATCH + b0 + row) * AD + (k - SD), bf);
      v = f2bf((x - mst[k * 2]) * mst[k * 2 + 1]);
    }
    sanb[idx] = v;
  }
  {
    const u32* src = (const u32*)(Wsa_t + (size_t)n * HID * KP3);
    u32* dst = (u32*)Wt;
    for (int idx = tid; idx < HID * KP3 / 2; idx += 256) dst[idx] = src[idx];
  }
  __syncthreads();
  {
    float4f acc[2][8] = {};
    #pragma unroll
    for (int kc = 0; kc < 3; kc++) {
      short8 a0 = *(const short8*)&sanb[((2 * w) * 16 + rl) * KP3 + kc * 32 + q * 8];
      short8 a1 = *(const short8*)&sanb[((2 * w + 1) * 16 + rl) * KP3 + kc * 32 + q * 8];
      #pragma unroll
      for (int nt = 0; nt < 8; nt++) {
        short8 bb = *(const short8*)&Wt[(nt * 16 + rl) * KP3 + kc * 32 + q * 8];
        acc[0][nt] = MFMA16(a0, bb, acc[0][nt]);
        acc[1][nt] = MFMA16(a1, bb, acc[1][nt]);
      }
    }
    #pragma unroll
    for (int mi = 0; mi < 2; mi++)
      #pragma unroll
      for (int nt = 0; nt < 8; nt++)
        #pragma unroll
        for (int r = 0; r < 4; r++) {
          int row = (2 * w + mi) * 16 + q * 4 + r, col = nt * 16 + rl;
          E[((size_t)n * BATCH + b0 + row) * HID + col] = f2bf(lrelu(acc[mi][nt][r] + bsaf[col]));
        }
  }
  __syncthreads();
  {
    const u32* src = (const u32*)(Wse_t + (size_t)n * HID * KPS);
    u32* dst = (u32*)Wt;
    for (int idx = tid; idx < HID * KPS / 2; idx += 256) dst[idx] = src[idx];
  }
  __syncthreads();
  {
    float4f acc[2][8] = {};
    #pragma unroll
    for (int kc = 0; kc < 2; kc++) {
      short8 a0 = *(const short8*)&sanb[((2 * w) * 16 + rl) * KP3 + kc * 32 + q * 8];
      short8 a1 = *(const short8*)&sanb[((2 * w + 1) * 16 + rl) * KP3 + kc * 32 + q * 8];
      #pragma unroll
      for (int nt = 0; nt < 8; nt++) {
        short8 bb = *(const short8*)&Wt[(nt * 16 + rl) * KPS + kc * 32 + q * 8];
        acc[0][nt] = MFMA16(a0, bb, acc[0][nt]);
        acc[1][nt] = MFMA16(a1, bb, acc[1][nt]);
      }
    }
    #pragma unroll
    for (int mi = 0; mi < 2; mi++)
      #pragma unroll
      for (int nt = 0; nt < 8; nt++)
        #pragma unroll
        for (int r = 0; r < 4; r++) {
          int row = (2 * w + mi) * 16 + q * 4 + r, col = nt * 16 + rl;
          SEo[((size_t)n * BATCH + b0 + row) * HID + col] = f2bf(lrelu(acc[mi][nt][r] + bsef[col]));
        }
  }
}

// ---------------- K4: fused projections + FULL-MFMA attention ----------------
// block = 8 batch x 8 agents. sel/key/val rows stored b-major: row' = b*8 + agent.
// Wave w owns b-pair {2w, 2w+1}: logits = 1 MFMA, softmax = shfl in C-regs,
// other = 2 MFMAs (w via LDS wb for C->A transform, K 16->32 zero-padded).
// LDS: X 17408 + Wh 17408 + selb 17408 + keyb 4352 + valt 4352 + wb 3072 + bvf 512 = 64512 B
__global__ __launch_bounds__(256) void k_pattn3(
    const u16* __restrict__ E, const u16* __restrict__ SEi,
    const u16* __restrict__ Wp_t, const void* __restrict__ bv_g,
    const int* __restrict__ flag, u16* __restrict__ OT) {
  __shared__ __align__(16) u16 X[64 * KP];
  __shared__ __align__(16) u16 Wh[64 * KP];
  __shared__ __align__(16) u16 selb[HEADS * 64 * SP];   // [p][row'=b*8+agent][d]
  __shared__ __align__(16) u16 keyb[64 * SP];           // [row'][d]
  __shared__ __align__(16) u16 valt[ATT * VTS];         // [d][row']
  __shared__ __align__(16) u16 wb[64 * WBS];            // [row'=(b,i)][n=(b,j)] softmax weights
  __shared__ float bvf[HID];
  bool bf = (*flag != 0);
  int tid = threadIdx.x;
  int b0 = blockIdx.x * 8;
  int w = tid >> 6, lane = tid & 63, q = lane >> 4, rl = lane & 15;

  if (tid < HID) bvf[tid] = ldin(bv_g, tid, bf);
  // stage X <- SE (agent-major rows: row = agent*8 + b)
  {
    const u32* su = (const u32*)SEi;
    for (int idx = tid; idx < 64 * 64; idx += 256) {
      int row = idx >> 6, c = idx & 63;
      ((u32*)&X[row * KP])[c] = su[(((size_t)(row >> 3)) * BATCH + b0 + (row & 7)) * 64 + c];
    }
  }
  // ---- phase 1: sel for all heads (2 heads per Wh staging) ----
  for (int pp = 0; pp < 2; pp++) {
    for (int idx = tid; idx < ATT * KP; idx += 256) {   // u32 count = 2 heads * ATT*KP/2
      int h = idx / (ATT * KP / 2), r = idx % (ATT * KP / 2);
      ((u32*)(Wh + h * ATT * KP))[r] = ((const u32*)(Wp_t + (size_t)(2 * pp + h) * 3 * ATT * KP))[r];
    }
    __syncthreads();
    #pragma unroll
    for (int h = 0; h < 2; h++) {
      int p = 2 * pp + h;
      float4f acs[2] = {};
      #pragma unroll
      for (int kc = 0; kc < 4; kc++) {
        short8 af = *(const short8*)&X[(w * 16 + rl) * KP + kc * 32 + q * 8];
        #pragma unroll
        for (int nt = 0; nt < 2; nt++) {
          short8 bb = *(const short8*)&Wh[(h * 32 + nt * 16 + rl) * KP + kc * 32 + q * 8];
          acs[nt] = MFMA16(af, bb, acs[nt]);
        }
      }
      #pragma unroll
      for (int nt = 0; nt < 2; nt++)
        #pragma unroll
        for (int r = 0; r < 4; r++) {
          int m = w * 16 + q * 4 + r;                 // agent-major row
          int rowp = ((m & 7) << 3) | (m >> 3);       // b-major row'
          selb[(p * 64 + rowp) * SP + nt * 16 + rl] = f2bf(acs[nt][r]);
        }
    }
    __syncthreads();
  }
  // restage X <- E
  {
    const u32* su = (const u32*)E;
    for (int idx = tid; idx < 64 * 64; idx += 256) {
      int row = idx >> 6, c = idx & 63;
      ((u32*)&X[row * KP])[c] = su[(((size_t)(row >> 3)) * BATCH + b0 + (row & 7)) * 64 + c];
    }
  }
  // ---- phase 2: per head: key+val proj -> MFMA logits -> shfl softmax -> MFMA weighted sum ----
  const float scale = 0.17677669529663687f;
  for (int p = 0; p < HEADS; p++) {
    for (int idx = tid; idx < ATT * KP; idx += 256)   // key||val contiguous (2 mats)
      ((u32*)Wh)[idx] = ((const u32*)(Wp_t + (size_t)(p * 3 + 1) * ATT * KP))[idx];
    __syncthreads();
    {
      float4f ak[2] = {}, av[2] = {};
      #pragma unroll
      for (int kc = 0; kc < 4; kc++) {
        short8 af = *(const short8*)&X[(w * 16 + rl) * KP + kc * 32 + q * 8];
        #pragma unroll
        for (int nt = 0; nt < 2; nt++) {
          short8 bk = *(const short8*)&Wh[(nt * 16 + rl) * KP + kc * 32 + q * 8];
          ak[nt] = MFMA16(af, bk, ak[nt]);
          short8 bv8 = *(const short8*)&Wh[((2 + nt) * 16 + rl) * KP + kc * 32 + q * 8];
          av[nt] = MFMA16(af, bv8, av[nt]);
        }
      }
      #pragma unroll
      for (int nt = 0; nt < 2; nt++)
        #pragma unroll
        for (int r = 0; r < 4; r++) {
          int m = w * 16 + q * 4 + r;
          int rowp = ((m & 7) << 3) | (m >> 3);
          int d = nt * 16 + rl;
          keyb[rowp * SP + d] = f2bf(ak[nt][r]);
          valt[d * VTS + rowp] = f2bf(lrelu(av[nt][r] + bvf[p * ATT + d]));
        }
    }
    __syncthreads();
    {
      // logits for b-pair w: C[m=(b,i)][n=(b,j)], K=32 (=ATT_D)
      short8 sa = lds_s8(&selb[(p * 64 + w * 16 + rl) * SP + q * 8]);
      short8 kb = lds_s8(&keyb[(w * 16 + rl) * SP + q * 8]);
      float4f zc = {};
      float4f c = MFMA16(sa, kb, zc);
      int n = rl;
      #pragma unroll
      for (int r = 0; r < 4; r++) {
        int row = q * 4 + r;
        float x = c[r] * scale;
        if (row == n) x = -1e9f;                     // self-mask (i==j, same b)
        float mx = x;
        mx = fmaxf(mx, __shfl_xor(mx, 1));
        mx = fmaxf(mx, __shfl_xor(mx, 2));
        mx = fmaxf(mx, __shfl_xor(mx, 4));           // max over the 8-lane j-group
        float e = __expf(x - mx);
        float ssum = e;
        ssum += __shfl_xor(ssum, 1);
        ssum += __shfl_xor(ssum, 2);
        ssum += __shfl_xor(ssum, 4);
        float wv = e / ssum;
        if ((row >> 3) != (n >> 3)) wv = 0.f;        // zero cross-b junk before MFMA reuse
        wb[(w * 16 + row) * WBS + n] = f2bf(wv);
      }
      // weighted sum: other[m][d] = sum_j w[m][j] val[(b,j)][d]; K=16 padded to 32
      short8 aw;
      if (q < 2) aw = *(const short8*)&wb[(w * 16 + rl) * WBS + q * 8];
      else { short8 z = {}; aw = z; }
      float4f o[2] = {};
      #pragma unroll
      for (int nt = 0; nt < 2; nt++) {
        // rows w*16 + (q&1)*8 + j are always valid/finite (q>=2 contributes 0 via aw=0)
        short8 bv8 = lds_s8(&valt[(nt * 16 + rl) * VTS + w * 16 + (q & 1) * 8]);
        o[nt] = MFMA16(aw, bv8, o[nt]);
      }
      #pragma unroll
      for (int nt = 0; nt < 2; nt++)
        #pragma unroll
        for (int r = 0; r < 4; r++) {
          int row = q * 4 + r;
          int b = 2 * w + (row >> 3), i = row & 7;
          OT[((size_t)i * BATCH + b0 + b) * HID + p * ATT + nt * 16 + rl] = f2bf(o[nt][r]);
        }
    }
    __syncthreads();   // keyb/valt/wb reads done before next head's proj writes (ordered via stage barrier)
  }
}

// ---------------- K5: critic MFMA GEMM + argmax gather (proven) ----------------
__global__ __launch_bounds__(256) void k_critic(
    const u16* __restrict__ SEi, const u16* __restrict__ OT, const void* __restrict__ a_g,
    const u16* __restrict__ Wc1t, const void* __restrict__ bc1_g,
    const void* __restrict__ Wc2_g, const void* __restrict__ bc2_g,
    const int* __restrict__ flag, void* __restrict__ qo) {
  __shared__ __align__(16) u16 Xt[128 * KP];
  __shared__ __align__(16) u16 W1t[128 * KPS];
  __shared__ float bc1f[HID];
  __shared__ int amax[128];
  bool bf = (*flag != 0);
  int tid = threadIdx.x;
  int n = blockIdx.y;
  int b0 = blockIdx.x * 128;
  int w = tid >> 6, lane = tid & 63, q = lane >> 4, rl = lane & 15;
  if (tid < HID) bc1f[tid] = ldin(bc1_g, n * HID + tid, bf);

  float4f acc[2][8] = {};
  for (int ph = 0; ph < 2; ph++) {
    const u32* su = (const u32*)(ph == 0 ? SEi : OT);
    for (int idx = tid; idx < 128 * 64; idx += 256) {
      int row = idx >> 6, c = idx & 63;
      ((u32*)&Xt[row * KP])[c] = su[((size_t)n * BATCH + b0 + row) * 64 + c];
    }
    for (int kh = 0; kh < 2; kh++) {
      for (int idx = tid; idx < 128 * 32; idx += 256) {
        int col = idx >> 5, kk2 = idx & 31;
        ((u32*)&W1t[col * KPS])[kk2] =
            ((const u32*)(Wc1t + ((size_t)n * HID + col) * 256 + ph * HID + kh * 64))[kk2];
      }
      __syncthreads();
      #pragma unroll
      for (int kc = 0; kc < 2; kc++) {
        short8 a0 = *(const short8*)&Xt[((2 * w) * 16 + rl) * KP + kh * 64 + kc * 32 + q * 8];
        short8 a1 = *(const short8*)&Xt[((2 * w + 1) * 16 + rl) * KP + kh * 64 + kc * 32 + q * 8];
        #pragma unroll
        for (int nt = 0; nt < 8; nt++) {
          short8 bb = *(const short8*)&W1t[(nt * 16 + rl) * KPS + kc * 32 + q * 8];
          acc[0][nt] = MFMA16(a0, bb, acc[0][nt]);
          acc[1][nt] = MFMA16(a1, bb, acc[1][nt]);
        }
      }
      __syncthreads();
    }
  }
  u16* ht = Xt;
  #pragma unroll
  for (int mi = 0; mi < 2; mi++)
    #pragma unroll
    for (int nt = 0; nt < 8; nt++)
      #pragma unroll
      for (int r = 0; r < 4; r++) {
        int row = (2 * w + mi) * 16 + q * 4 + r, col = nt * 16 + rl;
        ht[row * KP + col] = f2bf(lrelu(acc[mi][nt][r] + bc1f[col]));
      }
  float* wc2f = (float*)W1t;
  for (int idx = tid; idx < HID * AD; idx += 256)
    wc2f[idx] = ldin(Wc2_g, (size_t)n * HID * AD + idx, bf);
  if (tid < 128) {
    size_t base = ((size_t)n * BATCH + b0 + tid) * AD;
    float best = ldin(a_g, base, bf); int bi = 0;
    for (int o = 1; o < AD; o++) {
      float v = ldin(a_g, base + o, bf);
      if (v > best) { best = v; bi = o; }
    }
    amax[tid] = bi;
  }
  __syncthreads();
  {
    int b = tid >> 1, half = tid & 1;
    int col = amax[b];
    float acq = 0.f;
    const u16* hr = &ht[b * KP + half * 64];
    #pragma unroll
    for (int k = 0; k < 64; k++)
      acq = fmaf(bf2f(hr[k]), wc2f[(half * 64 + k) * AD + col], acq);
    acq += __shfl_xor(acq, 1);
    if (half == 0) {
      float v = acq + ldin(bc2_g, n * AD + col, bf);
      size_t oidx = (size_t)n * BATCH + b0 + b;
      if (bf) ((u16*)qo)[oidx] = f2bf(v);
      else    ((float*)qo)[oidx] = v;
    }
  }
}

extern "C" void kernel_launch(void* const* d_in, const int* in_sizes, int n_in,
                              void* d_out, int out_size, void* d_ws, size_t ws_size,
                              hipStream_t stream) {
  const void* s   = d_in[0];
  const void* a   = d_in[1];
  const void* Wsa = d_in[2];
  const void* bsa = d_in[3];
  const void* Wse = d_in[4];
  const void* bse = d_in[5];
  const void* Wk  = d_in[6];
  const void* Wsl = d_in[7];
  const void* Wv  = d_in[8];
  const void* bv  = d_in[9];
  const void* Wc1 = d_in[10];
  const void* bc1 = d_in[11];
  const void* Wc2 = d_in[12];
  const void* bc2 = d_in[13];

  char* ws = (char*)d_ws;
  int*   flag  = (int*)ws;
  float* part  = (float*)(ws + 256);
  float* mr    = (float*)(ws + 164096);
  u16*   Wsa_t = (u16*)(ws + 169216);
  u16*   Wse_t = (u16*)(ws + 382208);
  u16*   Wp_t  = (u16*)(ws + 529664);
  u16*   Wc1t  = (u16*)(ws + 634112);
  u16*   E     = (u16*)(ws + 1158400);
  u16*   SEb   = (u16*)(ws + 1158400 + 33554432ull);
  u16*   OT    = (u16*)(ws + 1158400 + 2ull * 33554432ull);

  k_detect<<<1, 64, 0, stream>>>((const u32*)s, flag);
  k_stats<<<256, 256, 0, stream>>>(s, a, flag, part);
  k_stats_fin<<<10, 64, 0, stream>>>(part, mr);
  k_wprep<<<(A1 + A2 + A3 + A4 + 255) / 256, 256, 0, stream>>>(
      Wsa, Wse, Wsl, Wk, Wv, Wc1, flag, Wsa_t, Wse_t, Wp_t, Wc1t);
  k_enc2<<<dim3(BATCH / 128, NA), 256, 0, stream>>>(s, a, Wsa_t, bsa, Wse_t, bse, mr, flag, E, SEb);
  k_pattn3<<<BATCH / 8, 256, 0, stream>>>(E, SEb, Wp_t, bv, flag, OT);
  k_critic<<<dim3(BATCH / 128, NA), 256, 0, stream>>>(SEb, OT, a, Wc1t, bc1, Wc2, bc2, flag, d_out);
}

// Round 6
// 286.433 us; speedup vs baseline: 5.7411x; 1.3682x over previous
//
#include <hip/hip_runtime.h>

// Attention_Critic on MI355X — round 6: no-LDS-weight-staging (direct global B-frags),
// tiled transpose wprep, folded detect/fin, 5 launches.
//
// ws layout (bytes):
//   [0,256)        int flag (1 = bf16 inputs, 0 = f32)
//   [256,+163840)  stats partials f32 [8][32][80][2]
//   [169216,...)   Wsa_t bf16 [8][128 col][104 k]
//   [382208,...)   Wse_t bf16 [8][128 col][72 k]
//   [529664,...)   Wp_t  bf16 [4 p][3 mat][32 d][136 k]  (mat 0=sel,1=key,2=val)
//   [634112,...)   Wc1t  bf16 [8][128 col][256 k]
//   [1158400,+32M) E   bf16 [8][16384][128]
//   [+32M,+64M)    SE  bf16 [8][16384][128]
//   [+64M,+96M)    OT  bf16 [8][16384][128]

typedef unsigned short u16;
typedef unsigned int u32;

#define NA 8
#define BATCH 16384
#define SD 64
#define AD 16
#define IND 80
#define HID 128
#define HEADS 4
#define ATT 32
#define EPS 1e-5f
#define KP 136    // u16 stride, 128-k tiles
#define KP3 104   // u16 stride, 96-k tiles
#define KPS 72    // u16 stride, 64-k tiles (Wse_t)
#define SP 34     // u16 stride, 32-wide sel/key tiles
#define VTS 68    // u16 stride, valt [32 d][64 row']
#define WBS 24    // u16 stride, per-wave softmax weight tiles

using short8 = __attribute__((ext_vector_type(8))) short;
using float4f = __attribute__((ext_vector_type(4))) float;
#define MFMA16(a, b, c) __builtin_amdgcn_mfma_f32_16x16x32_bf16((a), (b), (c), 0, 0, 0)

__device__ __forceinline__ float bf2f(u16 u) { union { u32 i; float f; } v; v.i = ((u32)u) << 16; return v.f; }
__device__ __forceinline__ float lo2f(u32 w) { union { u32 i; float f; } v; v.i = w << 16; return v.f; }
__device__ __forceinline__ float hi2f(u32 w) { union { u32 i; float f; } v; v.i = w & 0xffff0000u; return v.f; }
__device__ __forceinline__ u16 f2bf(float f) {
  union { float f; u32 i; } v; v.f = f;
  u32 x = v.i;
  x += 0x7fffu + ((x >> 16) & 1u);   // RNE
  return (u16)(x >> 16);
}
__device__ __forceinline__ float lrelu(float x) { return x > 0.f ? x : 0.01f * x; }
__device__ __forceinline__ float ldin(const void* p, size_t i, bool bf) {
  return bf ? bf2f(((const u16*)p)[i]) : ((const float*)p)[i];
}
__device__ __forceinline__ u16 ldbf(const void* p, size_t i, bool bf) {
  return bf ? ((const u16*)p)[i] : f2bf(((const float*)p)[i]);
}
__device__ __forceinline__ short8 lds_s8(const u16* p) {   // 16B LDS load from 4B-aligned addr
  union { short8 v; u32 u[4]; } t;
  const u32* q = (const u32*)p;
  t.u[0] = q[0]; t.u[1] = q[1]; t.u[2] = q[2]; t.u[3] = q[3];
  return t.v;
}

// ---------------- K1: BN stats + folded dtype detect ----------------
__global__ __launch_bounds__(256) void k_stats(const void* __restrict__ s, const void* __restrict__ a,
                                               int* __restrict__ flag, float* __restrict__ part) {
  __shared__ float S0[256], Q0[256], S1[256], Q1[256];
  __shared__ int cnt[2];
  int tid = threadIdx.x;
  if (tid < 2) cnt[tid] = 0;
  __syncthreads();
  {
    u32 wv = ((const u32*)s)[tid];
    u32 lo = wv & 0xffffu, e = (lo >> 7) & 0xffu;
    if (lo == 0u || lo == 0x8000u) atomicAdd(&cnt[1], 1);
    else if (e < 0x70u || e > 0x8fu) atomicAdd(&cnt[0], 1);
  }
  __syncthreads();
  bool bf = !(cnt[0] >= 64 || cnt[1] >= 192);
  if (blockIdx.x == 0 && tid == 0) *flag = bf ? 1 : 0;
  int blk = blockIdx.x, n = blk >> 5, c = blk & 31, b0 = c << 9;
  // s: 32 feature-pairs x 8 row-groups
  {
    int f2 = tid & 31, rg = tid >> 5;
    float s0 = 0.f, s1 = 0.f, q0 = 0.f, q1 = 0.f;
    for (int i = 0; i < 64; i++) {
      int b = b0 + rg + 8 * i;
      float x0, x1;
      if (bf) { u32 wv = ((const u32*)s)[((size_t)n * BATCH + b) * 32 + f2]; x0 = lo2f(wv); x1 = hi2f(wv); }
      else { const float* sf = (const float*)s + ((size_t)n * BATCH + b) * 64 + 2 * f2; x0 = sf[0]; x1 = sf[1]; }
      s0 += x0; q0 += x0 * x0; s1 += x1; q1 += x1 * x1;
    }
    S0[tid] = s0; Q0[tid] = q0; S1[tid] = s1; Q1[tid] = q1;
  }
  __syncthreads();
  if (tid < 64) {
    int f2 = tid >> 1, odd = tid & 1;
    float S = 0.f, Q = 0.f;
    for (int rg = 0; rg < 8; rg++) {
      int ix = rg * 32 + f2;
      S += odd ? S1[ix] : S0[ix];
      Q += odd ? Q1[ix] : Q0[ix];
    }
    float* p = part + ((size_t)blk * IND + tid) * 2;
    p[0] = S; p[1] = Q;
  }
  __syncthreads();
  // a: 8 feature-pairs x 32 row-groups
  {
    int f2 = tid & 7, rg = tid >> 3;
    float s0 = 0.f, s1 = 0.f, q0 = 0.f, q1 = 0.f;
    for (int i = 0; i < 16; i++) {
      int b = b0 + rg + 32 * i;
      float x0, x1;
      if (bf) { u32 wv = ((const u32*)a)[((size_t)n * BATCH + b) * 8 + f2]; x0 = lo2f(wv); x1 = hi2f(wv); }
      else { const float* af = (const float*)a + ((size_t)n * BATCH + b) * 16 + 2 * f2; x0 = af[0]; x1 = af[1]; }
      s0 += x0; q0 += x0 * x0; s1 += x1; q1 += x1 * x1;
    }
    S0[tid] = s0; Q0[tid] = q0; S1[tid] = s1; Q1[tid] = q1;
  }
  __syncthreads();
  if (tid < 16) {
    int f2 = tid >> 1, odd = tid & 1;
    float S = 0.f, Q = 0.f;
    for (int rg = 0; rg < 32; rg++) {
      int ix = rg * 8 + f2;
      S += odd ? S1[ix] : S0[ix];
      Q += odd ? Q1[ix] : Q0[ix];
    }
    float* p = part + ((size_t)blk * IND + SD + tid) * 2;
    p[0] = S; p[1] = Q;
  }
}

// ---------------- K2: weight prep — coalesced tiled LDS transpose ----------------
// blocks: [0,32) Wc1 (n, k-tile of 64); [32,40) Wsa; [40,48) Wse; [48,60) Wp (p,mat).
__global__ __launch_bounds__(256) void k_wprep(
    const void* __restrict__ Wsa, const void* __restrict__ Wse,
    const void* __restrict__ Wsl, const void* __restrict__ Wk, const void* __restrict__ Wv,
    const void* __restrict__ Wc1, const int* __restrict__ flag,
    u16* __restrict__ Wsa_t, u16* __restrict__ Wse_t, u16* __restrict__ Wp_t, u16* __restrict__ Wc1t) {
  __shared__ u16 T[80 * 130];
  bool bf = (*flag != 0);
  int tid = threadIdx.x;
  int blk = blockIdx.x;
  if (blk < 32) {                       // Wc1 [n][256][128] -> Wc1t [n][128][256]
    int n = blk >> 2, k0 = (blk & 3) * 64;
    for (int i = tid; i < 64 * 128; i += 256) {
      int kr = i >> 7, cc = i & 127;
      T[kr * 130 + cc] = ldbf(Wc1, ((size_t)n * 256 + k0 + kr) * 128 + cc, bf);
    }
    __syncthreads();
    for (int i = tid; i < 128 * 64; i += 256) {
      int col = i >> 6, kk = i & 63;
      Wc1t[((size_t)n * 128 + col) * 256 + k0 + kk] = T[kk * 130 + col];
    }
  } else if (blk < 40) {                // Wsa [n][80][128] -> Wsa_t [n][128][104]
    int n = blk - 32;
    for (int i = tid; i < 80 * 128; i += 256) {
      int kr = i >> 7, cc = i & 127;
      T[kr * 130 + cc] = ldbf(Wsa, ((size_t)n * IND + kr) * 128 + cc, bf);
    }
    __syncthreads();
    for (int i = tid; i < 128 * KP3; i += 256) {
      int col = i / KP3, k = i - col * KP3;
      Wsa_t[((size_t)n * 128 + col) * KP3 + k] = (k < IND) ? T[k * 130 + col] : (u16)0;
    }
  } else if (blk < 48) {                // Wse [n][64][128] -> Wse_t [n][128][72]
    int n = blk - 40;
    for (int i = tid; i < 64 * 128; i += 256) {
      int kr = i >> 7, cc = i & 127;
      T[kr * 130 + cc] = ldbf(Wse, ((size_t)n * SD + kr) * 128 + cc, bf);
    }
    __syncthreads();
    for (int i = tid; i < 128 * KPS; i += 256) {
      int col = i / KPS, k = i - col * KPS;
      Wse_t[((size_t)n * 128 + col) * KPS + k] = (k < SD) ? T[k * 130 + col] : (u16)0;
    }
  } else {                              // Wp [p][128][32] -> Wp_t [p][mat][32][136]
    int pm = blk - 48, p = pm / 3, mat = pm - 3 * p;
    const void* W = (mat == 0) ? Wsl : (mat == 1) ? Wk : Wv;
    for (int i = tid; i < 128 * 32; i += 256) {
      int kr = i >> 5, d = i & 31;
      T[kr * 34 + d] = ldbf(W, ((size_t)p * HID + kr) * ATT + d, bf);
    }
    __syncthreads();
    for (int i = tid; i < 32 * KP; i += 256) {
      int d = i / KP, k = i - d * KP;
      Wp_t[(((size_t)p * 3 + mat) * ATT + d) * KP + k] = (k < HID) ? T[k * 34 + d] : (u16)0;
    }
  }
}

// ---------------- K3: MFMA encoders, folded stats-finalize, direct-global B-frags ----------------
// block = 1 agent x 128 batch rows. LDS: sanb 26624 + mst 640 + biases 1024 = 28288 B (5 blocks/CU)
__global__ __launch_bounds__(256) void k_enc2(const void* __restrict__ s, const void* __restrict__ a,
    const u16* __restrict__ Wsa_t, const void* __restrict__ bsa,
    const u16* __restrict__ Wse_t, const void* __restrict__ bse,
    const float* __restrict__ part, const int* __restrict__ flag,
    u16* __restrict__ E, u16* __restrict__ SEo) {
  __shared__ __align__(16) u16 sanb[128 * KP3];
  __shared__ float mst[IND * 2];
  __shared__ float bsaf[HID], bsef[HID];
  bool bf = (*flag != 0);
  int tid = threadIdx.x;
  int n = blockIdx.y;
  int b0 = blockIdx.x * 128;
  int w = tid >> 6, lane = tid & 63, q = lane >> 4, rl = lane & 15;
  if (tid < HID) { bsaf[tid] = ldin(bsa, n * HID + tid, bf); bsef[tid] = ldin(bse, n * HID + tid, bf); }
  if (tid < IND) {   // folded stats finalize
    float S = 0.f, Q = 0.f;
    for (int c = 0; c < 32; c++) {
      const float* pp = part + ((size_t)(n * 32 + c) * IND + tid) * 2;
      S += pp[0]; Q += pp[1];
    }
    float mean = S * (1.f / BATCH);
    float var = Q * (1.f / BATCH) - mean * mean;
    mst[tid * 2] = mean;
    mst[tid * 2 + 1] = rsqrtf(var + EPS);
  }
  __syncthreads();
  // stage normalized rows, u32-vectorized
  for (int i = tid; i < 128 * 32; i += 256) {          // s-part: k 0..63
    int row = i >> 5, kp = i & 31;
    float x0, x1;
    if (bf) { u32 wv = ((const u32*)s)[((size_t)n * BATCH + b0 + row) * 32 + kp]; x0 = lo2f(wv); x1 = hi2f(wv); }
    else { const float* sf = (const float*)s + ((size_t)n * BATCH + b0 + row) * 64 + 2 * kp; x0 = sf[0]; x1 = sf[1]; }
    int k = 2 * kp;
    u32 o = (u32)f2bf((x0 - mst[k * 2]) * mst[k * 2 + 1]) |
            ((u32)f2bf((x1 - mst[k * 2 + 2]) * mst[k * 2 + 3]) << 16);
    *(u32*)&sanb[row * KP3 + k] = o;
  }
  for (int i = tid; i < 128 * 8; i += 256) {           // a-part: k 64..79
    int row = i >> 3, kp = i & 7;
    float x0, x1;
    if (bf) { u32 wv = ((const u32*)a)[((size_t)n * BATCH + b0 + row) * 8 + kp]; x0 = lo2f(wv); x1 = hi2f(wv); }
    else { const float* af = (const float*)a + ((size_t)n * BATCH + b0 + row) * 16 + 2 * kp; x0 = af[0]; x1 = af[1]; }
    int k = SD + 2 * kp;
    u32 o = (u32)f2bf((x0 - mst[k * 2]) * mst[k * 2 + 1]) |
            ((u32)f2bf((x1 - mst[k * 2 + 2]) * mst[k * 2 + 3]) << 16);
    *(u32*)&sanb[row * KP3 + k] = o;
  }
  for (int i = tid; i < 128 * 12; i += 256) {          // zero pad k 80..103
    int row = i / 12, c2 = i - row * 12;
    *(u32*)&sanb[row * KP3 + IND + 2 * c2] = 0u;
  }
  __syncthreads();
  const u16* WA = Wsa_t + (size_t)n * HID * KP3;
  const u16* WS = Wse_t + (size_t)n * HID * KPS;
  {  // E = lrelu(bn(sa) @ Wsa + bsa), K=96
    float4f acc[2][8] = {};
    #pragma unroll
    for (int kc = 0; kc < 3; kc++) {
      short8 a0 = *(const short8*)&sanb[((2 * w) * 16 + rl) * KP3 + kc * 32 + q * 8];
      short8 a1 = *(const short8*)&sanb[((2 * w + 1) * 16 + rl) * KP3 + kc * 32 + q * 8];
      #pragma unroll
      for (int nt = 0; nt < 8; nt++) {
        short8 bb = *(const short8*)(WA + (size_t)(nt * 16 + rl) * KP3 + kc * 32 + q * 8);
        acc[0][nt] = MFMA16(a0, bb, acc[0][nt]);
        acc[1][nt] = MFMA16(a1, bb, acc[1][nt]);
      }
    }
    #pragma unroll
    for (int mi = 0; mi < 2; mi++)
      #pragma unroll
      for (int nt = 0; nt < 8; nt++)
        #pragma unroll
        for (int r = 0; r < 4; r++) {
          int row = (2 * w + mi) * 16 + q * 4 + r, col = nt * 16 + rl;
          E[((size_t)n * BATCH + b0 + row) * HID + col] = f2bf(lrelu(acc[mi][nt][r] + bsaf[col]));
        }
  }
  {  // SE = lrelu(bn(s) @ Wse + bse), K=64
    float4f acc[2][8] = {};
    #pragma unroll
    for (int kc = 0; kc < 2; kc++) {
      short8 a0 = *(const short8*)&sanb[((2 * w) * 16 + rl) * KP3 + kc * 32 + q * 8];
      short8 a1 = *(const short8*)&sanb[((2 * w + 1) * 16 + rl) * KP3 + kc * 32 + q * 8];
      #pragma unroll
      for (int nt = 0; nt < 8; nt++) {
        short8 bb = *(const short8*)(WS + (size_t)(nt * 16 + rl) * KPS + kc * 32 + q * 8);
        acc[0][nt] = MFMA16(a0, bb, acc[0][nt]);
        acc[1][nt] = MFMA16(a1, bb, acc[1][nt]);
      }
    }
    #pragma unroll
    for (int mi = 0; mi < 2; mi++)
      #pragma unroll
      for (int nt = 0; nt < 8; nt++)
        #pragma unroll
        for (int r = 0; r < 4; r++) {
          int row = (2 * w + mi) * 16 + q * 4 + r, col = nt * 16 + rl;
          SEo[((size_t)n * BATCH + b0 + row) * HID + col] = f2bf(lrelu(acc[mi][nt][r] + bsef[col]));
        }
  }
}

// ---------------- K4: fused projections + full-MFMA attention, direct-global B-frags ----------------
// LDS: X 17408 + selb 17408 + keyb 4352 + valt 4352 + wb 3072 + bvf 512 = 47104 B (3 blocks/CU)
__global__ __launch_bounds__(256) void k_pattn4(
    const u16* __restrict__ E, const u16* __restrict__ SEi,
    const u16* __restrict__ Wp_t, const void* __restrict__ bv_g,
    const int* __restrict__ flag, u16* __restrict__ OT) {
  __shared__ __align__(16) u16 X[64 * KP];
  __shared__ __align__(16) u16 selb[HEADS * 64 * SP];   // [p][row'=b*8+agent][d]
  __shared__ __align__(16) u16 keyb[64 * SP];
  __shared__ __align__(16) u16 valt[ATT * VTS];         // [d][row']
  __shared__ __align__(16) u16 wb[64 * WBS];            // softmax weights
  __shared__ float bvf[HID];
  bool bf = (*flag != 0);
  int tid = threadIdx.x;
  int b0 = blockIdx.x * 8;
  int w = tid >> 6, lane = tid & 63, q = lane >> 4, rl = lane & 15;
  if (tid < HID) bvf[tid] = ldin(bv_g, tid, bf);
  // stage X <- SE
  {
    const u32* su = (const u32*)SEi;
    for (int idx = tid; idx < 64 * 64; idx += 256) {
      int row = idx >> 6, c = idx & 63;
      ((u32*)&X[row * KP])[c] = su[(((size_t)(row >> 3)) * BATCH + b0 + (row & 7)) * 64 + c];
    }
  }
  __syncthreads();
  // phase 1: sel for all heads, B-frags straight from global (no barriers inside)
  #pragma unroll
  for (int p = 0; p < HEADS; p++) {
    const u16* WB = Wp_t + (size_t)(p * 3) * ATT * KP;
    float4f acs[2] = {};
    #pragma unroll
    for (int kc = 0; kc < 4; kc++) {
      short8 af = *(const short8*)&X[(w * 16 + rl) * KP + kc * 32 + q * 8];
      #pragma unroll
      for (int nt = 0; nt < 2; nt++) {
        short8 bb = *(const short8*)(WB + (size_t)(nt * 16 + rl) * KP + kc * 32 + q * 8);
        acs[nt] = MFMA16(af, bb, acs[nt]);
      }
    }
    #pragma unroll
    for (int nt = 0; nt < 2; nt++)
      #pragma unroll
      for (int r = 0; r < 4; r++) {
        int m = w * 16 + q * 4 + r;
        int rowp = ((m & 7) << 3) | (m >> 3);
        selb[(p * 64 + rowp) * SP + nt * 16 + rl] = f2bf(acs[nt][r]);
      }
  }
  __syncthreads();
  // restage X <- E
  {
    const u32* su = (const u32*)E;
    for (int idx = tid; idx < 64 * 64; idx += 256) {
      int row = idx >> 6, c = idx & 63;
      ((u32*)&X[row * KP])[c] = su[(((size_t)(row >> 3)) * BATCH + b0 + (row & 7)) * 64 + c];
    }
  }
  __syncthreads();
  // phase 2: per head: key/val -> MFMA logits -> shfl softmax -> MFMA weighted sum
  const float scale = 0.17677669529663687f;
  for (int p = 0; p < HEADS; p++) {
    const u16* WK = Wp_t + (size_t)(p * 3 + 1) * ATT * KP;
    const u16* WV = Wp_t + (size_t)(p * 3 + 2) * ATT * KP;
    {
      float4f ak[2] = {}, av[2] = {};
      #pragma unroll
      for (int kc = 0; kc < 4; kc++) {
        short8 af = *(const short8*)&X[(w * 16 + rl) * KP + kc * 32 + q * 8];
        #pragma unroll
        for (int nt = 0; nt < 2; nt++) {
          short8 bk = *(const short8*)(WK + (size_t)(nt * 16 + rl) * KP + kc * 32 + q * 8);
          ak[nt] = MFMA16(af, bk, ak[nt]);
          short8 bv8 = *(const short8*)(WV + (size_t)(nt * 16 + rl) * KP + kc * 32 + q * 8);
          av[nt] = MFMA16(af, bv8, av[nt]);
        }
      }
      #pragma unroll
      for (int nt = 0; nt < 2; nt++)
        #pragma unroll
        for (int r = 0; r < 4; r++) {
          int m = w * 16 + q * 4 + r;
          int rowp = ((m & 7) << 3) | (m >> 3);
          int d = nt * 16 + rl;
          keyb[rowp * SP + d] = f2bf(ak[nt][r]);
          valt[d * VTS + rowp] = f2bf(lrelu(av[nt][r] + bvf[p * ATT + d]));
        }
    }
    __syncthreads();
    {
      short8 sa = lds_s8(&selb[(p * 64 + w * 16 + rl) * SP + q * 8]);
      short8 kb = lds_s8(&keyb[(w * 16 + rl) * SP + q * 8]);
      float4f zc = {};
      float4f c = MFMA16(sa, kb, zc);
      int nn = rl;
      #pragma unroll
      for (int r = 0; r < 4; r++) {
        int row = q * 4 + r;
        float x = c[r] * scale;
        if (row == nn) x = -1e9f;                    // self-mask (same b, i==j)
        float mx = x;
        mx = fmaxf(mx, __shfl_xor(mx, 1));
        mx = fmaxf(mx, __shfl_xor(mx, 2));
        mx = fmaxf(mx, __shfl_xor(mx, 4));
        float e = __expf(x - mx);
        float ssum = e;
        ssum += __shfl_xor(ssum, 1);
        ssum += __shfl_xor(ssum, 2);
        ssum += __shfl_xor(ssum, 4);
        float wv = e / ssum;
        if ((row >> 3) != (nn >> 3)) wv = 0.f;       // zero cross-b junk
        wb[(w * 16 + row) * WBS + nn] = f2bf(wv);
      }
      short8 aw;
      if (q < 2) aw = *(const short8*)&wb[(w * 16 + rl) * WBS + q * 8];
      else { short8 z = {}; aw = z; }
      float4f o[2] = {};
      #pragma unroll
      for (int nt = 0; nt < 2; nt++) {
        short8 bv8 = lds_s8(&valt[(nt * 16 + rl) * VTS + w * 16 + (q & 1) * 8]);
        o[nt] = MFMA16(aw, bv8, o[nt]);
      }
      #pragma unroll
      for (int nt = 0; nt < 2; nt++)
        #pragma unroll
        for (int r = 0; r < 4; r++) {
          int row = q * 4 + r;
          int b = 2 * w + (row >> 3), i = row & 7;
          OT[((size_t)i * BATCH + b0 + b) * HID + p * ATT + nt * 16 + rl] = f2bf(o[nt][r]);
        }
    }
    __syncthreads();   // protect keyb/valt for next head
  }
}

// ---------------- K5: critic MFMA GEMM + argmax gather, direct-global B-frags ----------------
// LDS: Xt 34816 + wc2f 8192 + bc1f 512 + amax 512 = 44032 B (3 blocks/CU)
__global__ __launch_bounds__(256) void k_critic(
    const u16* __restrict__ SEi, const u16* __restrict__ OT, const void* __restrict__ a_g,
    const u16* __restrict__ Wc1t, const void* __restrict__ bc1_g,
    const void* __restrict__ Wc2_g, const void* __restrict__ bc2_g,
    const int* __restrict__ flag, void* __restrict__ qo) {
  __shared__ __align__(16) u16 Xt[128 * KP];   // input rows; reused as ht
  __shared__ float wc2f[HID * AD];
  __shared__ float bc1f[HID];
  __shared__ int amax[128];
  bool bf = (*flag != 0);
  int tid = threadIdx.x;
  int n = blockIdx.y;
  int b0 = blockIdx.x * 128;
  int w = tid >> 6, lane = tid & 63, q = lane >> 4, rl = lane & 15;
  if (tid < HID) bc1f[tid] = ldin(bc1_g, n * HID + tid, bf);
  const u16* WT = Wc1t + (size_t)n * HID * 256;

  float4f acc[2][8] = {};
  for (int ph = 0; ph < 2; ph++) {
    const u32* su = (const u32*)(ph == 0 ? SEi : OT);
    for (int idx = tid; idx < 128 * 64; idx += 256) {
      int row = idx >> 6, c = idx & 63;
      ((u32*)&Xt[row * KP])[c] = su[((size_t)n * BATCH + b0 + row) * 64 + c];
    }
    __syncthreads();
    #pragma unroll
    for (int kc = 0; kc < 4; kc++) {
      int ko = ph * HID + kc * 32;
      short8 a0 = *(const short8*)&Xt[((2 * w) * 16 + rl) * KP + kc * 32 + q * 8];
      short8 a1 = *(const short8*)&Xt[((2 * w + 1) * 16 + rl) * KP + kc * 32 + q * 8];
      #pragma unroll
      for (int nt = 0; nt < 8; nt++) {
        short8 bb = *(const short8*)(WT + (size_t)(nt * 16 + rl) * 256 + ko + q * 8);
        acc[0][nt] = MFMA16(a0, bb, acc[0][nt]);
        acc[1][nt] = MFMA16(a1, bb, acc[1][nt]);
      }
    }
    __syncthreads();
  }
  u16* ht = Xt;
  #pragma unroll
  for (int mi = 0; mi < 2; mi++)
    #pragma unroll
    for (int nt = 0; nt < 8; nt++)
      #pragma unroll
      for (int r = 0; r < 4; r++) {
        int row = (2 * w + mi) * 16 + q * 4 + r, col = nt * 16 + rl;
        ht[row * KP + col] = f2bf(lrelu(acc[mi][nt][r] + bc1f[col]));
      }
  for (int idx = tid; idx < HID * AD; idx += 256)
    wc2f[idx] = ldin(Wc2_g, (size_t)n * HID * AD + idx, bf);
  if (tid < 128) {
    size_t base = ((size_t)n * BATCH + b0 + tid) * AD;
    float best = ldin(a_g, base, bf); int bi = 0;
    for (int o = 1; o < AD; o++) {
      float v = ldin(a_g, base + o, bf);
      if (v > best) { best = v; bi = o; }   // strict > = first-max
    }
    amax[tid] = bi;
  }
  __syncthreads();
  {
    int b = tid >> 1, half = tid & 1;
    int col = amax[b];
    float acq = 0.f;
    const u16* hr = &ht[b * KP + half * 64];
    #pragma unroll
    for (int k = 0; k < 64; k++)
      acq = fmaf(bf2f(hr[k]), wc2f[(half * 64 + k) * AD + col], acq);
    acq += __shfl_xor(acq, 1);
    if (half == 0) {
      float v = acq + ldin(bc2_g, n * AD + col, bf);
      size_t oidx = (size_t)n * BATCH + b0 + b;
      if (bf) ((u16*)qo)[oidx] = f2bf(v);
      else    ((float*)qo)[oidx] = v;
    }
  }
}

extern "C" void kernel_launch(void* const* d_in, const int* in_sizes, int n_in,
                              void* d_out, int out_size, void* d_ws, size_t ws_size,
                              hipStream_t stream) {
  const void* s   = d_in[0];
  const void* a   = d_in[1];
  const void* Wsa = d_in[2];
  const void* bsa = d_in[3];
  const void* Wse = d_in[4];
  const void* bse = d_in[5];
  const void* Wk  = d_in[6];
  const void* Wsl = d_in[7];
  const void* Wv  = d_in[8];
  const void* bv  = d_in[9];
  const void* Wc1 = d_in[10];
  const void* bc1 = d_in[11];
  const void* Wc2 = d_in[12];
  const void* bc2 = d_in[13];

  char* ws = (char*)d_ws;
  int*   flag  = (int*)ws;
  float* part  = (float*)(ws + 256);
  u16*   Wsa_t = (u16*)(ws + 169216);
  u16*   Wse_t = (u16*)(ws + 382208);
  u16*   Wp_t  = (u16*)(ws + 529664);
  u16*   Wc1t  = (u16*)(ws + 634112);
  u16*   E     = (u16*)(ws + 1158400);
  u16*   SEb   = (u16*)(ws + 1158400 + 33554432ull);
  u16*   OT    = (u16*)(ws + 1158400 + 2ull * 33554432ull);

  k_stats<<<256, 256, 0, stream>>>(s, a, flag, part);
  k_wprep<<<60, 256, 0, stream>>>(Wsa, Wse, Wsl, Wk, Wv, Wc1, flag, Wsa_t, Wse_t, Wp_t, Wc1t);
  k_enc2<<<dim3(BATCH / 128, NA), 256, 0, stream>>>(s, a, Wsa_t, bsa, Wse_t, bse, part, flag, E, SEb);
  k_pattn4<<<BATCH / 8, 256, 0, stream>>>(E, SEb, Wp_t, bv, flag, OT);
  k_critic<<<dim3(BATCH / 128, NA), 256, 0, stream>>>(SEb, OT, a, Wc1t, bc1, Wc2, bc2, flag, d_out);
}